// Round 12
// baseline (296.773 us; speedup 1.0000x reference)
//
#include <hip/hip_runtime.h>

#define B_ 4
#define S_ 1024
#define D_ 1024
#define H_ 16
#define DK_ 64

typedef __attribute__((ext_vector_type(8))) short short8;
typedef __attribute__((ext_vector_type(4))) float f32x4;
typedef __attribute__((ext_vector_type(16))) float f32x16;

// 16 chunks per bh covering 72 k-tiles: nibble i = chunk i's {qb, t0, nt}
#define QBPACK 0x7777666554433210ULL
#define T0PACK 0xC840A50605040000ULL
#define NTPACK 0x4444455665544642ULL
// per-qb: first chunk index (byte) and chunk count (nibble)
#define CBPACK  0x0C09070503020100ULL
#define NCHPACK 0x43222111U

static __device__ __forceinline__ unsigned bf16rne(float x) {
    unsigned b = __float_as_uint(x);
    return (b + 0x7FFFu + ((b >> 16) & 1u)) >> 16;
}

// ---------------------------------------------------------------------------
// W [1024][1024] fp32 -> Wt [n][k] bf16 (transpose + convert). z selects W.
// ---------------------------------------------------------------------------
__global__ __launch_bounds__(256) void transpose_cvt3(
    const float* __restrict__ W0, const float* __restrict__ W1,
    const float* __restrict__ W2, ushort* __restrict__ T0,
    ushort* __restrict__ T1, ushort* __restrict__ T2)
{
    __shared__ float ts[32][33];
    const float* W = (blockIdx.z == 0) ? W0 : (blockIdx.z == 1) ? W1 : W2;
    ushort*     Wt = (blockIdx.z == 0) ? T0 : (blockIdx.z == 1) ? T1 : T2;
    const int t  = threadIdx.x;
    const int k0 = blockIdx.y * 32, n0 = blockIdx.x * 32;
    const int r  = t >> 3, c4 = (t & 7) * 4;
    const float4 v = *reinterpret_cast<const float4*>(&W[(size_t)(k0 + r) * 1024 + n0 + c4]);
    ts[r][c4] = v.x; ts[r][c4 + 1] = v.y; ts[r][c4 + 2] = v.z; ts[r][c4 + 3] = v.w;
    __syncthreads();
    ushort4 o;
    o.x = (ushort)bf16rne(ts[c4    ][r]);
    o.y = (ushort)bf16rne(ts[c4 + 1][r]);
    o.z = (ushort)bf16rne(ts[c4 + 2][r]);
    o.w = (ushort)bf16rne(ts[c4 + 3][r]);
    *reinterpret_cast<ushort4*>(&Wt[(size_t)(n0 + r) * 1024 + k0 + c4]) = o;
}

// ---------------------------------------------------------------------------
// Merged QKV projection GEMM, fp32-A fused convert. SINGLE-buffered LDS
// (24 KB -> 6 blocks/CU = full residency for 1536 blocks; TLP hides the
// per-tile B-stage latency, m97/m114 style). A: 2 named reg sets with
// uniform wrap-around issue so all vmcnt counts are literal; B: gload_lds.
// bm 0..63 -> Q (x1/8, headed), 64..127 -> K (headed), 128..191 -> V (tr).
// ---------------------------------------------------------------------------
__global__ __launch_bounds__(256, 6) void gemm_qkv(
    const float* __restrict__ q, const float* __restrict__ k,
    const float* __restrict__ v, const ushort* __restrict__ Wqt,
    const ushort* __restrict__ Wvt, const float* __restrict__ bq,
    const float* __restrict__ bv, ushort* __restrict__ Qh,
    ushort* __restrict__ Kh, ushort* __restrict__ Vt)
{
    __shared__ ushort As[64 * 64];     //  8 KB
    __shared__ ushort Bs[128 * 64];    // 16 KB

    const int t    = threadIdx.x;
    const int lane = t & 63;
    const int w    = t >> 6;

    const int cpx     = gridDim.x >> 3;
    const int logical = (blockIdx.x & 7) * cpx + (blockIdx.x >> 3);
    const int bm = logical >> 3;
    const int bn = logical & 7;

    const int mode = bm >> 6;                 // 0=Q, 1=K, 2=V
    const float* Xf = (mode == 0) ? q : (mode == 1) ? k : v;
    const ushort* Wt = (mode == 2) ? Wvt : Wqt;
    const float* bias = (mode == 2) ? bv : bq;
    const int rbase = (bm & 63) * 64;

    const int srow   = lane >> 3;
    const int schunk = (lane & 7) ^ srow;
    const float* ap[2];
#pragma unroll
    for (int j = 0; j < 2; ++j)
        ap[j] = Xf + (size_t)(rbase + (j * 4 + w) * 8 + srow) * 1024 + schunk * 8;

    const ushort* bg[4];
#pragma unroll
    for (int j = 0; j < 4; ++j)
        bg[j] = Wt + (size_t)(bn * 128 + (j * 4 + w) * 8 + srow) * 1024 + schunk * 8;

    // two named A register sets (literal indices only)
    float4 s0x0, s0y0, s0x1, s0y1;
    float4 s1x0, s1y0, s1x1, s1y1;

#define A_ISSUE0(k0)                                                             \
    do {                                                                         \
        s0x0 = *reinterpret_cast<const float4*>(ap[0] + (k0));                   \
        s0y0 = *reinterpret_cast<const float4*>(ap[0] + (k0) + 4);               \
        s0x1 = *reinterpret_cast<const float4*>(ap[1] + (k0));                   \
        s0y1 = *reinterpret_cast<const float4*>(ap[1] + (k0) + 4);               \
    } while (0)

#define A_ISSUE1(k0)                                                             \
    do {                                                                         \
        s1x0 = *reinterpret_cast<const float4*>(ap[0] + (k0));                   \
        s1y0 = *reinterpret_cast<const float4*>(ap[0] + (k0) + 4);               \
        s1x1 = *reinterpret_cast<const float4*>(ap[1] + (k0));                   \
        s1y1 = *reinterpret_cast<const float4*>(ap[1] + (k0) + 4);               \
    } while (0)

#define B_STAGE(k0)                                                              \
    do {                                                                         \
        _Pragma("unroll")                                                        \
        for (int j = 0; j < 4; ++j)                                              \
            __builtin_amdgcn_global_load_lds(                                    \
                (__attribute__((address_space(1))) const void*)(bg[j] + (k0)),   \
                (__attribute__((address_space(3))) void*)&Bs[(j * 4 + w) * 512], \
                16, 0, 0);                                                       \
    } while (0)

#define A_WRITE_SET(X0, Y0, X1, Y1)                                              \
    do {                                                                         \
        union { unsigned u[4]; int4 v; } p0, p1;                                 \
        asm("v_cvt_pk_bf16_f32 %0, %1, %2" : "=v"(p0.u[0]) : "v"(X0.x), "v"(X0.y)); \
        asm("v_cvt_pk_bf16_f32 %0, %1, %2" : "=v"(p0.u[1]) : "v"(X0.z), "v"(X0.w)); \
        asm("v_cvt_pk_bf16_f32 %0, %1, %2" : "=v"(p0.u[2]) : "v"(Y0.x), "v"(Y0.y)); \
        asm("v_cvt_pk_bf16_f32 %0, %1, %2" : "=v"(p0.u[3]) : "v"(Y0.z), "v"(Y0.w)); \
        asm("v_cvt_pk_bf16_f32 %0, %1, %2" : "=v"(p1.u[0]) : "v"(X1.x), "v"(X1.y)); \
        asm("v_cvt_pk_bf16_f32 %0, %1, %2" : "=v"(p1.u[1]) : "v"(X1.z), "v"(X1.w)); \
        asm("v_cvt_pk_bf16_f32 %0, %1, %2" : "=v"(p1.u[2]) : "v"(Y1.x), "v"(Y1.y)); \
        asm("v_cvt_pk_bf16_f32 %0, %1, %2" : "=v"(p1.u[3]) : "v"(Y1.z), "v"(Y1.w)); \
        *reinterpret_cast<int4*>(&As[((0 * 4 + w) * 64 + lane) * 8]) = p0.v;     \
        *reinterpret_cast<int4*>(&As[((1 * 4 + w) * 64 + lane) * 8]) = p1.v;     \
    } while (0)

    const int fr = lane & 15;
    const int fk = lane >> 4;
    const int wm = w >> 1, wn = w & 1;

    f32x4 acc[2][4];
#pragma unroll
    for (int m = 0; m < 2; ++m)
#pragma unroll
        for (int n = 0; n < 4; ++n) acc[m][n] = (f32x4){0.f, 0.f, 0.f, 0.f};

#define MFMA_TILE()                                                              \
    do {                                                                         \
        _Pragma("unroll")                                                        \
        for (int ks = 0; ks < 2; ++ks) {                                         \
            short8 af[2], bf[4];                                                 \
            _Pragma("unroll")                                                    \
            for (int m = 0; m < 2; ++m) {                                        \
                const int row = wm * 32 + m * 16 + fr;                           \
                af[m] = *reinterpret_cast<const short8*>(                        \
                    &As[row * 64 + (((ks * 4 + fk) ^ (row & 7)) * 8)]);          \
            }                                                                    \
            _Pragma("unroll")                                                    \
            for (int n = 0; n < 4; ++n) {                                        \
                const int row = wn * 64 + n * 16 + fr;                           \
                bf[n] = *reinterpret_cast<const short8*>(                        \
                    &Bs[row * 64 + (((ks * 4 + fk) ^ (row & 7)) * 8)]);          \
            }                                                                    \
            __builtin_amdgcn_s_setprio(1);                                       \
            _Pragma("unroll")                                                    \
            for (int m = 0; m < 2; ++m)                                          \
                _Pragma("unroll")                                                \
                for (int n = 0; n < 4; ++n)                                      \
                    acc[m][n] = __builtin_amdgcn_mfma_f32_16x16x32_bf16(         \
                        af[m], bf[n], acc[m][n], 0, 0, 0);                       \
            __builtin_amdgcn_s_setprio(0);                                       \
        }                                                                        \
    } while (0)

    // body: entry outstanding = {A(kt):4 oldest, A(kt+1):4}; wrap-issue keeps
    // all counts uniform (dummy reload of tile 0 at the tail, harmless).
#define BODY(kt, AWSET, AISS)                                                    \
    do {                                                                         \
        asm volatile("s_waitcnt vmcnt(4)" ::: "memory");  /* A(kt) landed */     \
        __builtin_amdgcn_sched_barrier(0);                                       \
        AWSET;                                            /* A(kt) -> As */      \
        B_STAGE((kt) * 64);                               /* B(kt) -> Bs */      \
        AISS((((kt) + 2) & 15) * 64);                     /* A(kt+2) -> regs */  \
        asm volatile("s_waitcnt vmcnt(4) lgkmcnt(0)" ::: "memory"); /* B(kt)+A-writes */ \
        __builtin_amdgcn_s_barrier();                                            \
        __builtin_amdgcn_sched_barrier(0);                                       \
        MFMA_TILE();                                                             \
        __builtin_amdgcn_sched_barrier(0);                                       \
        __builtin_amdgcn_s_barrier();                                            \
        __builtin_amdgcn_sched_barrier(0);                                       \
    } while (0)

    A_ISSUE0(0);
    A_ISSUE1(64);
#pragma unroll 1
    for (int kt = 0; kt < 16; kt += 2) {
        BODY(kt,     A_WRITE_SET(s0x0, s0y0, s0x1, s0y1), A_ISSUE0);
        BODY(kt + 1, A_WRITE_SET(s1x0, s1y0, s1x1, s1y1), A_ISSUE1);
    }
#undef A_ISSUE0
#undef A_ISSUE1
#undef B_STAGE
#undef A_WRITE_SET
#undef MFMA_TILE
#undef BODY

#pragma unroll
    for (int m = 0; m < 2; ++m) {
        const int row0 = rbase + wm * 32 + m * 16 + fk * 4;
#pragma unroll
        for (int n = 0; n < 4; ++n) {
            const int col = bn * 128 + wn * 64 + n * 16 + fr;
            const float bc = bias[col];
            const int b_ = row0 >> 10, s0 = row0 & 1023;
            const int h  = col >> 6,   dk = col & 63;
            if (mode == 0) {
#pragma unroll
                for (int j = 0; j < 4; ++j)
                    Qh[(((size_t)b_ * H_ + h) * S_ + s0 + j) * DK_ + dk] =
                        (ushort)bf16rne((acc[m][n][j] + bc) * 0.125f);
            } else if (mode == 1) {
#pragma unroll
                for (int j = 0; j < 4; ++j)
                    Kh[(((size_t)b_ * H_ + h) * S_ + s0 + j) * DK_ + dk] =
                        (ushort)bf16rne(acc[m][n][j] + bc);
            } else {
                ushort4 pk;
                pk.x = (ushort)bf16rne(acc[m][n][0] + bc);
                pk.y = (ushort)bf16rne(acc[m][n][1] + bc);
                pk.z = (ushort)bf16rne(acc[m][n][2] + bc);
                pk.w = (ushort)bf16rne(acc[m][n][3] + bc);
                *reinterpret_cast<ushort4*>(
                    &Vt[(((size_t)b_ * H_ + h) * DK_ + dk) * S_ + s0]) = pk;
            }
        }
    }
}

// ---------------------------------------------------------------------------
// bf16-A MFMA GEMM (output projection): C = ctx @ Wt^T + bias + resid (fp32).
// ---------------------------------------------------------------------------
__global__ __launch_bounds__(256) void gemm_bf16a(
    const ushort* __restrict__ X, const ushort* __restrict__ Wt,
    const float* __restrict__ bias, const float* __restrict__ resid,
    float* __restrict__ out)
{
    __shared__ ushort As[2][64 * 64];
    __shared__ ushort Bs[2][128 * 64];

    const int t    = threadIdx.x;
    const int lane = t & 63;
    const int w    = t >> 6;

    const int cpx     = gridDim.x >> 3;
    const int logical = (blockIdx.x & 7) * cpx + (blockIdx.x >> 3);
    const int bm = logical >> 3;
    const int bn = logical & 7;

    const int srow   = lane >> 3;
    const int schunk = (lane & 7) ^ srow;
    const ushort* ag[2];
    const ushort* bg[4];
#pragma unroll
    for (int j = 0; j < 2; ++j)
        ag[j] = X  + (size_t)(bm * 64 + (j * 4 + w) * 8 + srow) * 1024 + schunk * 8;
#pragma unroll
    for (int j = 0; j < 4; ++j)
        bg[j] = Wt + (size_t)(bn * 128 + (j * 4 + w) * 8 + srow) * 1024 + schunk * 8;

#define STAGE(buf, k0)                                                           \
    do {                                                                         \
        _Pragma("unroll")                                                        \
        for (int j = 0; j < 2; ++j)                                              \
            __builtin_amdgcn_global_load_lds(                                    \
                (__attribute__((address_space(1))) const void*)(ag[j] + (k0)),   \
                (__attribute__((address_space(3))) void*)&As[buf][(j * 4 + w) * 512], \
                16, 0, 0);                                                       \
        _Pragma("unroll")                                                        \
        for (int j = 0; j < 4; ++j)                                              \
            __builtin_amdgcn_global_load_lds(                                    \
                (__attribute__((address_space(1))) const void*)(bg[j] + (k0)),   \
                (__attribute__((address_space(3))) void*)&Bs[buf][(j * 4 + w) * 512], \
                16, 0, 0);                                                       \
    } while (0)

    const int fr = lane & 15;
    const int fk = lane >> 4;
    const int wm = w >> 1, wn = w & 1;

    f32x4 acc[2][4];
#pragma unroll
    for (int m = 0; m < 2; ++m)
#pragma unroll
        for (int n = 0; n < 4; ++n) acc[m][n] = (f32x4){0.f, 0.f, 0.f, 0.f};

    STAGE(0, 0);
#pragma unroll 1
    for (int kt = 0; kt < 16; ++kt) {
        const int cur = kt & 1;
        if (kt + 1 < 16) {
            STAGE(cur ^ 1, (kt + 1) * 64);
            asm volatile("s_waitcnt vmcnt(6)" ::: "memory");
        } else {
            asm volatile("s_waitcnt vmcnt(0)" ::: "memory");
        }
        __builtin_amdgcn_s_barrier();
        __builtin_amdgcn_sched_barrier(0);
#pragma unroll
        for (int ks = 0; ks < 2; ++ks) {
            short8 af[2], bf[4];
#pragma unroll
            for (int m = 0; m < 2; ++m) {
                const int row = wm * 32 + m * 16 + fr;
                af[m] = *reinterpret_cast<const short8*>(
                    &As[cur][row * 64 + (((ks * 4 + fk) ^ (row & 7)) * 8)]);
            }
#pragma unroll
            for (int n = 0; n < 4; ++n) {
                const int row = wn * 64 + n * 16 + fr;
                bf[n] = *reinterpret_cast<const short8*>(
                    &Bs[cur][row * 64 + (((ks * 4 + fk) ^ (row & 7)) * 8)]);
            }
            __builtin_amdgcn_s_setprio(1);
#pragma unroll
            for (int m = 0; m < 2; ++m)
#pragma unroll
                for (int n = 0; n < 4; ++n)
                    acc[m][n] = __builtin_amdgcn_mfma_f32_16x16x32_bf16(
                        af[m], bf[n], acc[m][n], 0, 0, 0);
            __builtin_amdgcn_s_setprio(0);
        }
        __builtin_amdgcn_sched_barrier(0);
        __builtin_amdgcn_s_barrier();
        __builtin_amdgcn_sched_barrier(0);
    }
#undef STAGE

#pragma unroll
    for (int m = 0; m < 2; ++m) {
        const int row0 = bm * 64 + wm * 32 + m * 16 + fk * 4;
#pragma unroll
        for (int n = 0; n < 4; ++n) {
            const int col = bn * 128 + wn * 64 + n * 16 + fr;
            const float bc = bias[col];
#pragma unroll
            for (int j = 0; j < 4; ++j) {
                const int row = row0 + j;
                out[(size_t)row * 1024 + col] =
                    acc[m][n][j] + bc + resid[(size_t)row * 1024 + col];
            }
        }
    }
}

// ---------------------------------------------------------------------------
// MFMA bf16 flash attention v8 (unchanged): 1024 blocks (64 bh x 16
// table-driven chunks), fragment-major LDS, counted vmcnt dbuf, SW-first.
// ---------------------------------------------------------------------------
__global__ __launch_bounds__(256) void attn_mfma(
    const ushort* __restrict__ Qh, const ushort* __restrict__ Kh,
    const ushort* __restrict__ Vt, const float* __restrict__ SW,
    ushort* __restrict__ ctxP, float2* __restrict__ ml)
{
    __shared__ ushort Ks[2][4096];
    __shared__ ushort Vs[2][4096];

    const int t    = threadIdx.x;
    const int lane = t & 63;
    const int w    = t >> 6;
    const int lg = (blockIdx.x & 7) * 128 + (blockIdx.x >> 3);
    const int b  = lg & 3;
    const int hc = lg >> 2;
    const int h  = hc >> 4;
    const int ci = hc & 15;
    const int bh = b * 16 + h;
    const int qb = (int)((QBPACK >> (ci * 4)) & 15);
    const int t0 = (int)((T0PACK >> (ci * 4)) & 15);
    const int nt = (int)((NTPACK >> (ci * 4)) & 15);

    const int ql = lane & 31;
    const int hi = lane >> 5;
    const int qrow = qb * 128 + ql * 4 + w;

    const ushort* Kg  = Kh + (size_t)bh * S_ * DK_;
    const ushort* Vg  = Vt + (size_t)bh * DK_ * S_;
    const float*  swp = SW + ((size_t)h * S_ + qrow) * S_;

    const ushort* kgp[2];
    const ushort* vgp[2];
#pragma unroll
    for (int j = 0; j < 2; ++j) {
        const int bb = w * 2 + j;
        const int g = bb >> 2, c = bb & 3;
        kgp[j] = Kg + (size_t)(g * 32 + ql) * DK_ + c * 16 + hi * 8;
        vgp[j] = Vg + (size_t)(g * 32 + ql) * S_  + c * 16 + hi * 8;
    }

#define ASTAGE(buf, k0)                                                          \
    do {                                                                         \
        _Pragma("unroll")                                                        \
        for (int j = 0; j < 2; ++j) {                                            \
            const int bb = w * 2 + j;                                            \
            __builtin_amdgcn_global_load_lds(                                    \
                (__attribute__((address_space(1))) const void*)(kgp[j] + (size_t)(k0) * DK_), \
                (__attribute__((address_space(3))) void*)&Ks[buf][bb * 512],     \
                16, 0, 0);                                                       \
            __builtin_amdgcn_global_load_lds(                                    \
                (__attribute__((address_space(1))) const void*)(vgp[j] + (k0)),  \
                (__attribute__((address_space(3))) void*)&Vs[buf][bb * 512],     \
                16, 0, 0);                                                       \
        }                                                                        \
    } while (0)

    short8 qf[4];
    {
        const ushort* Qg = Qh + ((size_t)bh * S_ + qrow) * DK_;
#pragma unroll
        for (int c = 0; c < 4; ++c) {
            union { int4 i; short8 s; } u;
            u.i = *reinterpret_cast<const int4*>(&Qg[c * 16 + hi * 8]);
            qf[c] = u.s;
        }
    }

    f32x16 accA, accB;
#pragma unroll
    for (int r = 0; r < 16; ++r) { accA[r] = 0.f; accB[r] = 0.f; }
    float mrow = -1e30f, lrow = 0.f;

    ASTAGE(0, t0 * 64);

#pragma unroll 1
    for (int kt = 0; kt < nt; ++kt) {
        const int cur = kt & 1;
        const int k0  = (t0 + kt) * 64;
        if (kt + 1 < nt) {
            ASTAGE(cur ^ 1, (t0 + kt + 1) * 64);
            asm volatile("s_waitcnt vmcnt(4)" ::: "memory");
        } else {
            asm volatile("s_waitcnt vmcnt(0)" ::: "memory");
        }
        __builtin_amdgcn_s_barrier();
        __builtin_amdgcn_sched_barrier(0);

        float swv[2][16];
#pragma unroll
        for (int g = 0; g < 2; ++g)
#pragma unroll
            for (int j = 0; j < 4; ++j) {
                const float4 v = *reinterpret_cast<const float4*>(
                    &swp[k0 + g * 32 + hi * 4 + j * 8]);
                swv[g][j * 4 + 0] = v.x; swv[g][j * 4 + 1] = v.y;
                swv[g][j * 4 + 2] = v.z; swv[g][j * 4 + 3] = v.w;
            }

        f32x16 sc[2];
        __builtin_amdgcn_s_setprio(1);
#pragma unroll
        for (int g = 0; g < 2; ++g) {
#pragma unroll
            for (int r = 0; r < 16; ++r) sc[g][r] = 0.f;
#pragma unroll
            for (int c = 0; c < 4; ++c) {
                const short8 kf = *reinterpret_cast<const short8*>(
                    &Ks[cur][((g * 4 + c) * 64 + lane) * 8]);
                sc[g] = __builtin_amdgcn_mfma_f32_32x32x16_bf16(kf, qf[c], sc[g], 0, 0, 0);
            }
        }
        __builtin_amdgcn_s_setprio(0);

        float pr[2][16];
        float tmax = -1e30f;
        if (t0 + kt >= 2 * qb) {
#pragma unroll
            for (int g = 0; g < 2; ++g)
#pragma unroll
                for (int r = 0; r < 16; ++r) {
                    const int key = k0 + g * 32 + (r & 3) + ((r >> 2) << 3) + (hi << 2);
                    const float s = (key < qrow) ? sc[g][r] + swv[g][r] : -1e30f;
                    pr[g][r] = s;
                    tmax = fmaxf(tmax, s);
                }
        } else {
#pragma unroll
            for (int g = 0; g < 2; ++g)
#pragma unroll
                for (int r = 0; r < 16; ++r) {
                    const float s = sc[g][r] + swv[g][r];
                    pr[g][r] = s;
                    tmax = fmaxf(tmax, s);
                }
        }
        tmax = fmaxf(tmax, __shfl_xor(tmax, 32, 64));
        const float mnew = fmaxf(mrow, tmax);
        const float corr = __expf(mrow - mnew);
        float psum = 0.f;
#pragma unroll
        for (int g = 0; g < 2; ++g)
#pragma unroll
            for (int r = 0; r < 16; ++r) {
                const float e = (pr[g][r] > -1e29f) ? __expf(pr[g][r] - mnew) : 0.f;
                pr[g][r] = e;
                psum += e;
            }
        psum += __shfl_xor(psum, 32, 64);
        lrow = lrow * corr + psum;
        mrow = mnew;
#pragma unroll
        for (int r = 0; r < 16; ++r) { accA[r] *= corr; accB[r] *= corr; }

        short8 paf[4];
#pragma unroll
        for (int g = 0; g < 2; ++g) {
            unsigned pk[8];
#pragma unroll
            for (int j = 0; j < 8; ++j) {
                unsigned r_;
                asm("v_cvt_pk_bf16_f32 %0, %1, %2"
                    : "=v"(r_) : "v"(pr[g][2 * j]), "v"(pr[g][2 * j + 1]));
                pk[j] = r_;
            }
            unsigned x0 = (unsigned)__shfl_xor((int)pk[0], 32, 64);
            unsigned x1 = (unsigned)__shfl_xor((int)pk[1], 32, 64);
            unsigned x2 = (unsigned)__shfl_xor((int)pk[2], 32, 64);
            unsigned x3 = (unsigned)__shfl_xor((int)pk[3], 32, 64);
            unsigned x4 = (unsigned)__shfl_xor((int)pk[4], 32, 64);
            unsigned x5 = (unsigned)__shfl_xor((int)pk[5], 32, 64);
            unsigned x6 = (unsigned)__shfl_xor((int)pk[6], 32, 64);
            unsigned x7 = (unsigned)__shfl_xor((int)pk[7], 32, 64);
            union { unsigned u[4]; short8 s; } a0, a1;
            a0.u[0] = hi ? x2 : pk[0];
            a0.u[1] = hi ? x3 : pk[1];
            a0.u[2] = hi ? pk[2] : x0;
            a0.u[3] = hi ? pk[3] : x1;
            a1.u[0] = hi ? x6 : pk[4];
            a1.u[1] = hi ? x7 : pk[5];
            a1.u[2] = hi ? pk[6] : x4;
            a1.u[3] = hi ? pk[7] : x5;
            paf[g * 2 + 0] = a0.s;
            paf[g * 2 + 1] = a1.s;
        }

        __builtin_amdgcn_s_setprio(1);
#pragma unroll
        for (int cc = 0; cc < 4; ++cc) {
            const short8 va = *reinterpret_cast<const short8*>(
                &Vs[cur][((0 * 4 + cc) * 64 + lane) * 8]);
            const short8 vb = *reinterpret_cast<const short8*>(
                &Vs[cur][((1 * 4 + cc) * 64 + lane) * 8]);
            accA = __builtin_amdgcn_mfma_f32_32x32x16_bf16(va, paf[cc], accA, 0, 0, 0);
            accB = __builtin_amdgcn_mfma_f32_32x32x16_bf16(vb, paf[cc], accB, 0, 0, 0);
        }
        __builtin_amdgcn_s_setprio(0);

        __builtin_amdgcn_sched_barrier(0);
        __builtin_amdgcn_s_barrier();
        __builtin_amdgcn_sched_barrier(0);
    }
#undef ASTAGE

    const float inv = (lrow > 0.f) ? 1.f / lrow : 0.f;
    ushort* crow_ = ctxP + ((size_t)(bh * 16 + ci) * 128 + (ql * 4 + w)) * 64;
#pragma unroll
    for (int g = 0; g < 4; ++g) {
        ushort4 oA, oB;
        oA.x = (ushort)bf16rne(accA[4 * g + 0] * inv);
        oA.y = (ushort)bf16rne(accA[4 * g + 1] * inv);
        oA.z = (ushort)bf16rne(accA[4 * g + 2] * inv);
        oA.w = (ushort)bf16rne(accA[4 * g + 3] * inv);
        oB.x = (ushort)bf16rne(accB[4 * g + 0] * inv);
        oB.y = (ushort)bf16rne(accB[4 * g + 1] * inv);
        oB.z = (ushort)bf16rne(accB[4 * g + 2] * inv);
        oB.w = (ushort)bf16rne(accB[4 * g + 3] * inv);
        *reinterpret_cast<ushort4*>(&crow_[g * 8 + hi * 4])      = oA;
        *reinterpret_cast<ushort4*>(&crow_[g * 8 + hi * 4 + 32]) = oB;
    }
    if (hi == 0) {
        float2 v; v.x = mrow; v.y = lrow;
        ml[(size_t)(bh * 16 + ci) * 128 + ql * 4 + w] = v;
    }
}

// ---------------------------------------------------------------------------
// Merge chunk partials (1..4 per q-row): out = sum_c w_c * o_c.
// ---------------------------------------------------------------------------
__global__ __launch_bounds__(256) void attn_merge(
    const ushort* __restrict__ ctxP, const float2* __restrict__ ml,
    ushort* __restrict__ ctx)
{
    const size_t idx = ((size_t)blockIdx.x * 256 + threadIdx.x) * 8;
    const int col = (int)(idx & 1023);
    const int row = (int)(idx >> 10);
    const int b = row >> 10, s = row & 1023;
    const int h = col >> 6, dk0 = col & 63;
    const int bh = b * 16 + h;
    const int qb = s >> 7, rl = s & 127;
    const int nch = (int)((NCHPACK >> (qb * 4)) & 15);
    const int cb  = (int)((CBPACK >> (qb * 8)) & 255);

    float mm[4], ll[4];
    float m = -1e30f;
#pragma unroll
    for (int c = 0; c < 4; ++c)
        if (c < nch) {
            const float2 v = ml[(size_t)(bh * 16 + cb + c) * 128 + rl];
            mm[c] = v.x; ll[c] = v.y;
            m = fmaxf(m, v.x);
        }
    float wc[4], wsum = 0.f;
#pragma unroll
    for (int c = 0; c < 4; ++c)
        if (c < nch) { wc[c] = ll[c] * __expf(mm[c] - m); wsum += wc[c]; }
    const float inv = (wsum > 0.f) ? 1.f / wsum : 0.f;

    float o[8] = {0.f, 0.f, 0.f, 0.f, 0.f, 0.f, 0.f, 0.f};
#pragma unroll
    for (int c = 0; c < 4; ++c)
        if (c < nch) {
            union { int4 v; ushort u[8]; } p;
            p.v = *reinterpret_cast<const int4*>(
                &ctxP[((size_t)(bh * 16 + cb + c) * 128 + rl) * 64 + dk0]);
            const float wgt = wc[c] * inv;
#pragma unroll
            for (int i = 0; i < 8; ++i)
                o[i] += wgt * __uint_as_float((unsigned)p.u[i] << 16);
        }
    union { int4 v; ushort u[8]; } r;
#pragma unroll
    for (int i = 0; i < 8; ++i) r.u[i] = (ushort)bf16rne(o[i]);
    *reinterpret_cast<int4*>(ctx + idx) = r.v;
}

// ---------------------------------------------------------------------------
// LayerNorm over last dim (1024).
// ---------------------------------------------------------------------------
__global__ __launch_bounds__(256) void layernorm_k(
    const float* __restrict__ x, const float* __restrict__ gamma,
    const float* __restrict__ beta, float* __restrict__ out)
{
    const int row = blockIdx.x;
    const int t   = threadIdx.x;
    const float4 v = *reinterpret_cast<const float4*>(&x[(size_t)row * D_ + (t << 2)]);
    float sum = v.x + v.y + v.z + v.w;
    float sq  = v.x * v.x + v.y * v.y + v.z * v.z + v.w * v.w;
#pragma unroll
    for (int w = 1; w < 64; w <<= 1) {
        sum += __shfl_xor(sum, w, 64);
        sq  += __shfl_xor(sq,  w, 64);
    }
    __shared__ float red[8];
    const int wid = t >> 6;
    if ((t & 63) == 0) { red[wid] = sum; red[wid + 4] = sq; }
    __syncthreads();
    sum = red[0] + red[1] + red[2] + red[3];
    sq  = red[4] + red[5] + red[6] + red[7];
    const float mu  = sum * (1.f / 1024.f);
    const float var = sq * (1.f / 1024.f) - mu * mu;
    const float rs  = rsqrtf(var + 1e-5f);
    const float4 gm = *reinterpret_cast<const float4*>(&gamma[t << 2]);
    const float4 bt = *reinterpret_cast<const float4*>(&beta[t << 2]);
    float4 o;
    o.x = (v.x - mu) * rs * gm.x + bt.x;
    o.y = (v.y - mu) * rs * gm.y + bt.y;
    o.z = (v.z - mu) * rs * gm.z + bt.z;
    o.w = (v.w - mu) * rs * gm.w + bt.w;
    *reinterpret_cast<float4*>(&out[(size_t)row * D_ + (t << 2)]) = o;
}

// ---------------------------------------------------------------------------
extern "C" void kernel_launch(void* const* d_in, const int* in_sizes, int n_in,
                              void* d_out, int out_size, void* d_ws, size_t ws_size,
                              hipStream_t stream)
{
    const float* query  = (const float*)d_in[0];
    const float* key    = (const float*)d_in[1];
    const float* values = (const float*)d_in[2];
    const float* SW     = (const float*)d_in[4];
    const float* Wq     = (const float*)d_in[5];
    const float* bq     = (const float*)d_in[6];
    const float* Wv     = (const float*)d_in[7];
    const float* bv     = (const float*)d_in[8];
    const float* Wo     = (const float*)d_in[9];
    const float* bo     = (const float*)d_in[10];
    const float* gamma  = (const float*)d_in[11];
    const float* beta   = (const float*)d_in[12];

    char* ws = (char*)d_ws;
    const size_t MB = 1024 * 1024;
    ushort* Qh   = (ushort*)(ws);              //  8 MB bf16 [bh][S][DK] (pre-scaled 1/8)
    ushort* Kh   = (ushort*)(ws +  8 * MB);
    ushort* Vt   = (ushort*)(ws + 16 * MB);    //  8 MB bf16 [bh][DK][S]
    ushort* Wqt  = (ushort*)(ws + 24 * MB);    //  2 MB each
    ushort* Wvt  = (ushort*)(ws + 26 * MB);
    ushort* Wot  = (ushort*)(ws + 28 * MB);
    ushort* ctxP = (ushort*)(ws + 30 * MB);    // 16 MB partials (30..46)
    float2* ml   = (float2*)(ws + 46 * MB);    //  1 MB
    ushort* ctxm = Qh;                         //  8 MB merged, overlays Qh (dead post-attn)
    float*  xbf  = (float*)(ws + 8 * MB);      // 16 MB fp32, overlays Kh|Vt (dead post-attn)

    const dim3 blk(256);

    transpose_cvt3<<<dim3(32, 32, 3), blk, 0, stream>>>(Wq, Wv, Wo, Wqt, Wvt, Wot);

    gemm_qkv<<<dim3(1536), blk, 0, stream>>>(query, key, values, Wqt, Wvt,
                                             bq, bv, Qh, Kh, Vt);

    attn_mfma<<<dim3(1024), blk, 0, stream>>>(Qh, Kh, Vt, SW, ctxP, ml);
    attn_merge<<<dim3(2048), blk, 0, stream>>>(ctxP, ml, ctxm);

    gemm_bf16a<<<dim3(512), blk, 0, stream>>>(ctxm, Wot, bo, query, xbf);

    layernorm_k<<<dim3(4096), blk, 0, stream>>>(xbf, gamma, beta, (float*)d_out);
}

// Round 14
// 128.572 us; speedup vs baseline: 2.3082x; 2.3082x over previous
//
#include <hip/hip_runtime.h>

#define B_ 4
#define S_ 1024
#define D_ 1024
#define H_ 16
#define DK_ 64

typedef __attribute__((ext_vector_type(8))) short short8;
typedef __attribute__((ext_vector_type(4))) float f32x4;
typedef __attribute__((ext_vector_type(16))) float f32x16;

// 16 chunks per bh covering 72 k-tiles: nibble i = chunk i's {qb, t0, nt}
#define QBPACK 0x7777666554433210ULL
#define T0PACK 0xC840A50605040000ULL
#define NTPACK 0x4444455665544642ULL
// per-qb: first chunk index (byte) and chunk count (nibble)
#define CBPACK  0x0C09070503020100ULL
#define NCHPACK 0x43222111U

static __device__ __forceinline__ unsigned bf16rne(float x) {
    unsigned b = __float_as_uint(x);
    return (b + 0x7FFFu + ((b >> 16) & 1u)) >> 16;
}

// ---------------------------------------------------------------------------
// W [1024][1024] fp32 -> Wt [n][k] bf16 (transpose + convert). z selects W.
// ---------------------------------------------------------------------------
__global__ __launch_bounds__(256) void transpose_cvt3(
    const float* __restrict__ W0, const float* __restrict__ W1,
    const float* __restrict__ W2, ushort* __restrict__ T0,
    ushort* __restrict__ T1, ushort* __restrict__ T2)
{
    __shared__ float ts[32][33];
    const float* W = (blockIdx.z == 0) ? W0 : (blockIdx.z == 1) ? W1 : W2;
    ushort*     Wt = (blockIdx.z == 0) ? T0 : (blockIdx.z == 1) ? T1 : T2;
    const int t  = threadIdx.x;
    const int k0 = blockIdx.y * 32, n0 = blockIdx.x * 32;
    const int r  = t >> 3, c4 = (t & 7) * 4;
    const float4 v = *reinterpret_cast<const float4*>(&W[(size_t)(k0 + r) * 1024 + n0 + c4]);
    ts[r][c4] = v.x; ts[r][c4 + 1] = v.y; ts[r][c4 + 2] = v.z; ts[r][c4 + 3] = v.w;
    __syncthreads();
    ushort4 o;
    o.x = (ushort)bf16rne(ts[c4    ][r]);
    o.y = (ushort)bf16rne(ts[c4 + 1][r]);
    o.z = (ushort)bf16rne(ts[c4 + 2][r]);
    o.w = (ushort)bf16rne(ts[c4 + 3][r]);
    *reinterpret_cast<ushort4*>(&Wt[(size_t)(n0 + r) * 1024 + k0 + c4]) = o;
}

// ---------------------------------------------------------------------------
// Merged QKV projection GEMM, fp32-A fused convert. SINGLE-buffered LDS
// (24 KB) + __launch_bounds__(256,5) -> 5 blocks/CU (20 waves/CU); TLP hides
// per-tile B-stage latency. ONE A reg set (no spill). Issue order inside the
// body is PINNED with sched_barrier(0) so vmcnt(4) provably drains B_STAGE
// (R13's NaN was the compiler reordering A-loads before B's global_load_lds).
// bm 0..63 -> Q (x1/8, headed), 64..127 -> K (headed), 128..191 -> V (tr).
// ---------------------------------------------------------------------------
__global__ __launch_bounds__(256, 5) void gemm_qkv(
    const float* __restrict__ q, const float* __restrict__ k,
    const float* __restrict__ v, const ushort* __restrict__ Wqt,
    const ushort* __restrict__ Wvt, const float* __restrict__ bq,
    const float* __restrict__ bv, ushort* __restrict__ Qh,
    ushort* __restrict__ Kh, ushort* __restrict__ Vt)
{
    __shared__ ushort As[64 * 64];     //  8 KB
    __shared__ ushort Bs[128 * 64];    // 16 KB

    const int t    = threadIdx.x;
    const int lane = t & 63;
    const int w    = t >> 6;

    const int cpx     = gridDim.x >> 3;
    const int logical = (blockIdx.x & 7) * cpx + (blockIdx.x >> 3);
    const int bm = logical >> 3;
    const int bn = logical & 7;

    const int mode = bm >> 6;                 // 0=Q, 1=K, 2=V
    const float* Xf = (mode == 0) ? q : (mode == 1) ? k : v;
    const ushort* Wt = (mode == 2) ? Wvt : Wqt;
    const float* bias = (mode == 2) ? bv : bq;
    const int rbase = (bm & 63) * 64;

    const int srow   = lane >> 3;
    const int schunk = (lane & 7) ^ srow;
    const float* ap[2];
#pragma unroll
    for (int j = 0; j < 2; ++j)
        ap[j] = Xf + (size_t)(rbase + (j * 4 + w) * 8 + srow) * 1024 + schunk * 8;

    const ushort* bg[4];
#pragma unroll
    for (int j = 0; j < 4; ++j)
        bg[j] = Wt + (size_t)(bn * 128 + (j * 4 + w) * 8 + srow) * 1024 + schunk * 8;

    // ONE named A register set (4x float4 = 16 VGPR)
    float4 aX0, aY0, aX1, aY1;

#define A_ISSUE(k0)                                                              \
    do {                                                                         \
        aX0 = *reinterpret_cast<const float4*>(ap[0] + (k0));                    \
        aY0 = *reinterpret_cast<const float4*>(ap[0] + (k0) + 4);                \
        aX1 = *reinterpret_cast<const float4*>(ap[1] + (k0));                    \
        aY1 = *reinterpret_cast<const float4*>(ap[1] + (k0) + 4);                \
    } while (0)

#define B_STAGE(k0)                                                              \
    do {                                                                         \
        _Pragma("unroll")                                                        \
        for (int j = 0; j < 4; ++j)                                              \
            __builtin_amdgcn_global_load_lds(                                    \
                (__attribute__((address_space(1))) const void*)(bg[j] + (k0)),   \
                (__attribute__((address_space(3))) void*)&Bs[(j * 4 + w) * 512], \
                16, 0, 0);                                                       \
    } while (0)

#define A_WRITE()                                                                \
    do {                                                                         \
        union { unsigned u[4]; int4 v; } p0, p1;                                 \
        asm("v_cvt_pk_bf16_f32 %0, %1, %2" : "=v"(p0.u[0]) : "v"(aX0.x), "v"(aX0.y)); \
        asm("v_cvt_pk_bf16_f32 %0, %1, %2" : "=v"(p0.u[1]) : "v"(aX0.z), "v"(aX0.w)); \
        asm("v_cvt_pk_bf16_f32 %0, %1, %2" : "=v"(p0.u[2]) : "v"(aY0.x), "v"(aY0.y)); \
        asm("v_cvt_pk_bf16_f32 %0, %1, %2" : "=v"(p0.u[3]) : "v"(aY0.z), "v"(aY0.w)); \
        asm("v_cvt_pk_bf16_f32 %0, %1, %2" : "=v"(p1.u[0]) : "v"(aX1.x), "v"(aX1.y)); \
        asm("v_cvt_pk_bf16_f32 %0, %1, %2" : "=v"(p1.u[1]) : "v"(aX1.z), "v"(aX1.w)); \
        asm("v_cvt_pk_bf16_f32 %0, %1, %2" : "=v"(p1.u[2]) : "v"(aY1.x), "v"(aY1.y)); \
        asm("v_cvt_pk_bf16_f32 %0, %1, %2" : "=v"(p1.u[3]) : "v"(aY1.z), "v"(aY1.w)); \
        *reinterpret_cast<int4*>(&As[((0 * 4 + w) * 64 + lane) * 8]) = p0.v;     \
        *reinterpret_cast<int4*>(&As[((1 * 4 + w) * 64 + lane) * 8]) = p1.v;     \
    } while (0)

    const int fr = lane & 15;
    const int fk = lane >> 4;
    const int wm = w >> 1, wn = w & 1;

    f32x4 acc[2][4];
#pragma unroll
    for (int m = 0; m < 2; ++m)
#pragma unroll
        for (int n = 0; n < 4; ++n) acc[m][n] = (f32x4){0.f, 0.f, 0.f, 0.f};

#define MFMA_TILE()                                                              \
    do {                                                                         \
        _Pragma("unroll")                                                        \
        for (int ks = 0; ks < 2; ++ks) {                                         \
            short8 af[2], bf[4];                                                 \
            _Pragma("unroll")                                                    \
            for (int m = 0; m < 2; ++m) {                                        \
                const int row = wm * 32 + m * 16 + fr;                           \
                af[m] = *reinterpret_cast<const short8*>(                        \
                    &As[row * 64 + (((ks * 4 + fk) ^ (row & 7)) * 8)]);          \
            }                                                                    \
            _Pragma("unroll")                                                    \
            for (int n = 0; n < 4; ++n) {                                        \
                const int row = wn * 64 + n * 16 + fr;                           \
                bf[n] = *reinterpret_cast<const short8*>(                        \
                    &Bs[row * 64 + (((ks * 4 + fk) ^ (row & 7)) * 8)]);          \
            }                                                                    \
            __builtin_amdgcn_s_setprio(1);                                       \
            _Pragma("unroll")                                                    \
            for (int m = 0; m < 2; ++m)                                          \
                _Pragma("unroll")                                                \
                for (int n = 0; n < 4; ++n)                                      \
                    acc[m][n] = __builtin_amdgcn_mfma_f32_16x16x32_bf16(         \
                        af[m], bf[n], acc[m][n], 0, 0, 0);                       \
            __builtin_amdgcn_s_setprio(0);                                       \
        }                                                                        \
    } while (0)

    // per-tile body; entry outstanding = A(kt) only (issued last iter).
    // sched_barrier(0) pins issue order: A_WRITE | B_STAGE | A_ISSUE | waits,
    // so vmcnt(4) provably drains the 4 B_STAGE ops (A(kt+1) stays in flight).
#define BODY(kt)                                                                 \
    do {                                                                         \
        asm volatile("s_waitcnt vmcnt(0)" ::: "memory");  /* A(kt) landed */     \
        __builtin_amdgcn_sched_barrier(0);                                       \
        A_WRITE();                                        /* A(kt) -> As */      \
        __builtin_amdgcn_sched_barrier(0);                                       \
        B_STAGE((kt) * 64);                               /* B(kt) -> Bs */      \
        __builtin_amdgcn_sched_barrier(0);                                       \
        A_ISSUE((((kt) + 1) & 15) * 64);                  /* A(kt+1) -> regs */  \
        __builtin_amdgcn_sched_barrier(0);                                       \
        asm volatile("s_waitcnt vmcnt(4) lgkmcnt(0)" ::: "memory"); /* B done */ \
        __builtin_amdgcn_s_barrier();                                            \
        __builtin_amdgcn_sched_barrier(0);                                       \
        MFMA_TILE();                                                             \
        __builtin_amdgcn_sched_barrier(0);                                       \
        __builtin_amdgcn_s_barrier();                                            \
        __builtin_amdgcn_sched_barrier(0);                                       \
    } while (0)

    A_ISSUE(0);
#pragma unroll 1
    for (int kt = 0; kt < 16; ++kt) {
        BODY(kt);
    }
#undef A_ISSUE
#undef B_STAGE
#undef A_WRITE
#undef MFMA_TILE
#undef BODY

#pragma unroll
    for (int m = 0; m < 2; ++m) {
        const int row0 = rbase + wm * 32 + m * 16 + fk * 4;
#pragma unroll
        for (int n = 0; n < 4; ++n) {
            const int col = bn * 128 + wn * 64 + n * 16 + fr;
            const float bc = bias[col];
            const int b_ = row0 >> 10, s0 = row0 & 1023;
            const int h  = col >> 6,   dk = col & 63;
            if (mode == 0) {
#pragma unroll
                for (int j = 0; j < 4; ++j)
                    Qh[(((size_t)b_ * H_ + h) * S_ + s0 + j) * DK_ + dk] =
                        (ushort)bf16rne((acc[m][n][j] + bc) * 0.125f);
            } else if (mode == 1) {
#pragma unroll
                for (int j = 0; j < 4; ++j)
                    Kh[(((size_t)b_ * H_ + h) * S_ + s0 + j) * DK_ + dk] =
                        (ushort)bf16rne(acc[m][n][j] + bc);
            } else {
                ushort4 pk;
                pk.x = (ushort)bf16rne(acc[m][n][0] + bc);
                pk.y = (ushort)bf16rne(acc[m][n][1] + bc);
                pk.z = (ushort)bf16rne(acc[m][n][2] + bc);
                pk.w = (ushort)bf16rne(acc[m][n][3] + bc);
                *reinterpret_cast<ushort4*>(
                    &Vt[(((size_t)b_ * H_ + h) * DK_ + dk) * S_ + s0]) = pk;
            }
        }
    }
}

// ---------------------------------------------------------------------------
// bf16-A MFMA GEMM (output projection): C = ctx @ Wt^T + bias + resid (fp32).
// ---------------------------------------------------------------------------
__global__ __launch_bounds__(256) void gemm_bf16a(
    const ushort* __restrict__ X, const ushort* __restrict__ Wt,
    const float* __restrict__ bias, const float* __restrict__ resid,
    float* __restrict__ out)
{
    __shared__ ushort As[2][64 * 64];
    __shared__ ushort Bs[2][128 * 64];

    const int t    = threadIdx.x;
    const int lane = t & 63;
    const int w    = t >> 6;

    const int cpx     = gridDim.x >> 3;
    const int logical = (blockIdx.x & 7) * cpx + (blockIdx.x >> 3);
    const int bm = logical >> 3;
    const int bn = logical & 7;

    const int srow   = lane >> 3;
    const int schunk = (lane & 7) ^ srow;
    const ushort* ag[2];
    const ushort* bg[4];
#pragma unroll
    for (int j = 0; j < 2; ++j)
        ag[j] = X  + (size_t)(bm * 64 + (j * 4 + w) * 8 + srow) * 1024 + schunk * 8;
#pragma unroll
    for (int j = 0; j < 4; ++j)
        bg[j] = Wt + (size_t)(bn * 128 + (j * 4 + w) * 8 + srow) * 1024 + schunk * 8;

#define STAGE(buf, k0)                                                           \
    do {                                                                         \
        _Pragma("unroll")                                                        \
        for (int j = 0; j < 2; ++j)                                              \
            __builtin_amdgcn_global_load_lds(                                    \
                (__attribute__((address_space(1))) const void*)(ag[j] + (k0)),   \
                (__attribute__((address_space(3))) void*)&As[buf][(j * 4 + w) * 512], \
                16, 0, 0);                                                       \
        _Pragma("unroll")                                                        \
        for (int j = 0; j < 4; ++j)                                              \
            __builtin_amdgcn_global_load_lds(                                    \
                (__attribute__((address_space(1))) const void*)(bg[j] + (k0)),   \
                (__attribute__((address_space(3))) void*)&Bs[buf][(j * 4 + w) * 512], \
                16, 0, 0);                                                       \
    } while (0)

    const int fr = lane & 15;
    const int fk = lane >> 4;
    const int wm = w >> 1, wn = w & 1;

    f32x4 acc[2][4];
#pragma unroll
    for (int m = 0; m < 2; ++m)
#pragma unroll
        for (int n = 0; n < 4; ++n) acc[m][n] = (f32x4){0.f, 0.f, 0.f, 0.f};

    STAGE(0, 0);
#pragma unroll 1
    for (int kt = 0; kt < 16; ++kt) {
        const int cur = kt & 1;
        if (kt + 1 < 16) {
            STAGE(cur ^ 1, (kt + 1) * 64);
            asm volatile("s_waitcnt vmcnt(6)" ::: "memory");
        } else {
            asm volatile("s_waitcnt vmcnt(0)" ::: "memory");
        }
        __builtin_amdgcn_s_barrier();
        __builtin_amdgcn_sched_barrier(0);
#pragma unroll
        for (int ks = 0; ks < 2; ++ks) {
            short8 af[2], bf[4];
#pragma unroll
            for (int m = 0; m < 2; ++m) {
                const int row = wm * 32 + m * 16 + fr;
                af[m] = *reinterpret_cast<const short8*>(
                    &As[cur][row * 64 + (((ks * 4 + fk) ^ (row & 7)) * 8)]);
            }
#pragma unroll
            for (int n = 0; n < 4; ++n) {
                const int row = wn * 64 + n * 16 + fr;
                bf[n] = *reinterpret_cast<const short8*>(
                    &Bs[cur][row * 64 + (((ks * 4 + fk) ^ (row & 7)) * 8)]);
            }
            __builtin_amdgcn_s_setprio(1);
#pragma unroll
            for (int m = 0; m < 2; ++m)
#pragma unroll
                for (int n = 0; n < 4; ++n)
                    acc[m][n] = __builtin_amdgcn_mfma_f32_16x16x32_bf16(
                        af[m], bf[n], acc[m][n], 0, 0, 0);
            __builtin_amdgcn_s_setprio(0);
        }
        __builtin_amdgcn_sched_barrier(0);
        __builtin_amdgcn_s_barrier();
        __builtin_amdgcn_sched_barrier(0);
    }
#undef STAGE

#pragma unroll
    for (int m = 0; m < 2; ++m) {
        const int row0 = bm * 64 + wm * 32 + m * 16 + fk * 4;
#pragma unroll
        for (int n = 0; n < 4; ++n) {
            const int col = bn * 128 + wn * 64 + n * 16 + fr;
            const float bc = bias[col];
#pragma unroll
            for (int j = 0; j < 4; ++j) {
                const int row = row0 + j;
                out[(size_t)row * 1024 + col] =
                    acc[m][n][j] + bc + resid[(size_t)row * 1024 + col];
            }
        }
    }
}

// ---------------------------------------------------------------------------
// MFMA bf16 flash attention v8 (unchanged): 1024 blocks (64 bh x 16
// table-driven chunks), fragment-major LDS, counted vmcnt dbuf, SW-first.
// ---------------------------------------------------------------------------
__global__ __launch_bounds__(256) void attn_mfma(
    const ushort* __restrict__ Qh, const ushort* __restrict__ Kh,
    const ushort* __restrict__ Vt, const float* __restrict__ SW,
    ushort* __restrict__ ctxP, float2* __restrict__ ml)
{
    __shared__ ushort Ks[2][4096];
    __shared__ ushort Vs[2][4096];

    const int t    = threadIdx.x;
    const int lane = t & 63;
    const int w    = t >> 6;
    const int lg = (blockIdx.x & 7) * 128 + (blockIdx.x >> 3);
    const int b  = lg & 3;
    const int hc = lg >> 2;
    const int h  = hc >> 4;
    const int ci = hc & 15;
    const int bh = b * 16 + h;
    const int qb = (int)((QBPACK >> (ci * 4)) & 15);
    const int t0 = (int)((T0PACK >> (ci * 4)) & 15);
    const int nt = (int)((NTPACK >> (ci * 4)) & 15);

    const int ql = lane & 31;
    const int hi = lane >> 5;
    const int qrow = qb * 128 + ql * 4 + w;

    const ushort* Kg  = Kh + (size_t)bh * S_ * DK_;
    const ushort* Vg  = Vt + (size_t)bh * DK_ * S_;
    const float*  swp = SW + ((size_t)h * S_ + qrow) * S_;

    const ushort* kgp[2];
    const ushort* vgp[2];
#pragma unroll
    for (int j = 0; j < 2; ++j) {
        const int bb = w * 2 + j;
        const int g = bb >> 2, c = bb & 3;
        kgp[j] = Kg + (size_t)(g * 32 + ql) * DK_ + c * 16 + hi * 8;
        vgp[j] = Vg + (size_t)(g * 32 + ql) * S_  + c * 16 + hi * 8;
    }

#define ASTAGE(buf, k0)                                                          \
    do {                                                                         \
        _Pragma("unroll")                                                        \
        for (int j = 0; j < 2; ++j) {                                            \
            const int bb = w * 2 + j;                                            \
            __builtin_amdgcn_global_load_lds(                                    \
                (__attribute__((address_space(1))) const void*)(kgp[j] + (size_t)(k0) * DK_), \
                (__attribute__((address_space(3))) void*)&Ks[buf][bb * 512],     \
                16, 0, 0);                                                       \
            __builtin_amdgcn_global_load_lds(                                    \
                (__attribute__((address_space(1))) const void*)(vgp[j] + (k0)),  \
                (__attribute__((address_space(3))) void*)&Vs[buf][bb * 512],     \
                16, 0, 0);                                                       \
        }                                                                        \
    } while (0)

    short8 qf[4];
    {
        const ushort* Qg = Qh + ((size_t)bh * S_ + qrow) * DK_;
#pragma unroll
        for (int c = 0; c < 4; ++c) {
            union { int4 i; short8 s; } u;
            u.i = *reinterpret_cast<const int4*>(&Qg[c * 16 + hi * 8]);
            qf[c] = u.s;
        }
    }

    f32x16 accA, accB;
#pragma unroll
    for (int r = 0; r < 16; ++r) { accA[r] = 0.f; accB[r] = 0.f; }
    float mrow = -1e30f, lrow = 0.f;

    ASTAGE(0, t0 * 64);

#pragma unroll 1
    for (int kt = 0; kt < nt; ++kt) {
        const int cur = kt & 1;
        const int k0  = (t0 + kt) * 64;
        if (kt + 1 < nt) {
            ASTAGE(cur ^ 1, (t0 + kt + 1) * 64);
            asm volatile("s_waitcnt vmcnt(4)" ::: "memory");
        } else {
            asm volatile("s_waitcnt vmcnt(0)" ::: "memory");
        }
        __builtin_amdgcn_s_barrier();
        __builtin_amdgcn_sched_barrier(0);

        float swv[2][16];
#pragma unroll
        for (int g = 0; g < 2; ++g)
#pragma unroll
            for (int j = 0; j < 4; ++j) {
                const float4 v = *reinterpret_cast<const float4*>(
                    &swp[k0 + g * 32 + hi * 4 + j * 8]);
                swv[g][j * 4 + 0] = v.x; swv[g][j * 4 + 1] = v.y;
                swv[g][j * 4 + 2] = v.z; swv[g][j * 4 + 3] = v.w;
            }

        f32x16 sc[2];
        __builtin_amdgcn_s_setprio(1);
#pragma unroll
        for (int g = 0; g < 2; ++g) {
#pragma unroll
            for (int r = 0; r < 16; ++r) sc[g][r] = 0.f;
#pragma unroll
            for (int c = 0; c < 4; ++c) {
                const short8 kf = *reinterpret_cast<const short8*>(
                    &Ks[cur][((g * 4 + c) * 64 + lane) * 8]);
                sc[g] = __builtin_amdgcn_mfma_f32_32x32x16_bf16(kf, qf[c], sc[g], 0, 0, 0);
            }
        }
        __builtin_amdgcn_s_setprio(0);

        float pr[2][16];
        float tmax = -1e30f;
        if (t0 + kt >= 2 * qb) {
#pragma unroll
            for (int g = 0; g < 2; ++g)
#pragma unroll
                for (int r = 0; r < 16; ++r) {
                    const int key = k0 + g * 32 + (r & 3) + ((r >> 2) << 3) + (hi << 2);
                    const float s = (key < qrow) ? sc[g][r] + swv[g][r] : -1e30f;
                    pr[g][r] = s;
                    tmax = fmaxf(tmax, s);
                }
        } else {
#pragma unroll
            for (int g = 0; g < 2; ++g)
#pragma unroll
                for (int r = 0; r < 16; ++r) {
                    const float s = sc[g][r] + swv[g][r];
                    pr[g][r] = s;
                    tmax = fmaxf(tmax, s);
                }
        }
        tmax = fmaxf(tmax, __shfl_xor(tmax, 32, 64));
        const float mnew = fmaxf(mrow, tmax);
        const float corr = __expf(mrow - mnew);
        float psum = 0.f;
#pragma unroll
        for (int g = 0; g < 2; ++g)
#pragma unroll
            for (int r = 0; r < 16; ++r) {
                const float e = (pr[g][r] > -1e29f) ? __expf(pr[g][r] - mnew) : 0.f;
                pr[g][r] = e;
                psum += e;
            }
        psum += __shfl_xor(psum, 32, 64);
        lrow = lrow * corr + psum;
        mrow = mnew;
#pragma unroll
        for (int r = 0; r < 16; ++r) { accA[r] *= corr; accB[r] *= corr; }

        short8 paf[4];
#pragma unroll
        for (int g = 0; g < 2; ++g) {
            unsigned pk[8];
#pragma unroll
            for (int j = 0; j < 8; ++j) {
                unsigned r_;
                asm("v_cvt_pk_bf16_f32 %0, %1, %2"
                    : "=v"(r_) : "v"(pr[g][2 * j]), "v"(pr[g][2 * j + 1]));
                pk[j] = r_;
            }
            unsigned x0 = (unsigned)__shfl_xor((int)pk[0], 32, 64);
            unsigned x1 = (unsigned)__shfl_xor((int)pk[1], 32, 64);
            unsigned x2 = (unsigned)__shfl_xor((int)pk[2], 32, 64);
            unsigned x3 = (unsigned)__shfl_xor((int)pk[3], 32, 64);
            unsigned x4 = (unsigned)__shfl_xor((int)pk[4], 32, 64);
            unsigned x5 = (unsigned)__shfl_xor((int)pk[5], 32, 64);
            unsigned x6 = (unsigned)__shfl_xor((int)pk[6], 32, 64);
            unsigned x7 = (unsigned)__shfl_xor((int)pk[7], 32, 64);
            union { unsigned u[4]; short8 s; } a0, a1;
            a0.u[0] = hi ? x2 : pk[0];
            a0.u[1] = hi ? x3 : pk[1];
            a0.u[2] = hi ? pk[2] : x0;
            a0.u[3] = hi ? pk[3] : x1;
            a1.u[0] = hi ? x6 : pk[4];
            a1.u[1] = hi ? x7 : pk[5];
            a1.u[2] = hi ? pk[6] : x4;
            a1.u[3] = hi ? pk[7] : x5;
            paf[g * 2 + 0] = a0.s;
            paf[g * 2 + 1] = a1.s;
        }

        __builtin_amdgcn_s_setprio(1);
#pragma unroll
        for (int cc = 0; cc < 4; ++cc) {
            const short8 va = *reinterpret_cast<const short8*>(
                &Vs[cur][((0 * 4 + cc) * 64 + lane) * 8]);
            const short8 vb = *reinterpret_cast<const short8*>(
                &Vs[cur][((1 * 4 + cc) * 64 + lane) * 8]);
            accA = __builtin_amdgcn_mfma_f32_32x32x16_bf16(va, paf[cc], accA, 0, 0, 0);
            accB = __builtin_amdgcn_mfma_f32_32x32x16_bf16(vb, paf[cc], accB, 0, 0, 0);
        }
        __builtin_amdgcn_s_setprio(0);

        __builtin_amdgcn_sched_barrier(0);
        __builtin_amdgcn_s_barrier();
        __builtin_amdgcn_sched_barrier(0);
    }
#undef ASTAGE

    const float inv = (lrow > 0.f) ? 1.f / lrow : 0.f;
    ushort* crow_ = ctxP + ((size_t)(bh * 16 + ci) * 128 + (ql * 4 + w)) * 64;
#pragma unroll
    for (int g = 0; g < 4; ++g) {
        ushort4 oA, oB;
        oA.x = (ushort)bf16rne(accA[4 * g + 0] * inv);
        oA.y = (ushort)bf16rne(accA[4 * g + 1] * inv);
        oA.z = (ushort)bf16rne(accA[4 * g + 2] * inv);
        oA.w = (ushort)bf16rne(accA[4 * g + 3] * inv);
        oB.x = (ushort)bf16rne(accB[4 * g + 0] * inv);
        oB.y = (ushort)bf16rne(accB[4 * g + 1] * inv);
        oB.z = (ushort)bf16rne(accB[4 * g + 2] * inv);
        oB.w = (ushort)bf16rne(accB[4 * g + 3] * inv);
        *reinterpret_cast<ushort4*>(&crow_[g * 8 + hi * 4])      = oA;
        *reinterpret_cast<ushort4*>(&crow_[g * 8 + hi * 4 + 32]) = oB;
    }
    if (hi == 0) {
        float2 v; v.x = mrow; v.y = lrow;
        ml[(size_t)(bh * 16 + ci) * 128 + ql * 4 + w] = v;
    }
}

// ---------------------------------------------------------------------------
// Merge chunk partials (1..4 per q-row): out = sum_c w_c * o_c.
// ---------------------------------------------------------------------------
__global__ __launch_bounds__(256) void attn_merge(
    const ushort* __restrict__ ctxP, const float2* __restrict__ ml,
    ushort* __restrict__ ctx)
{
    const size_t idx = ((size_t)blockIdx.x * 256 + threadIdx.x) * 8;
    const int col = (int)(idx & 1023);
    const int row = (int)(idx >> 10);
    const int b = row >> 10, s = row & 1023;
    const int h = col >> 6, dk0 = col & 63;
    const int bh = b * 16 + h;
    const int qb = s >> 7, rl = s & 127;
    const int nch = (int)((NCHPACK >> (qb * 4)) & 15);
    const int cb  = (int)((CBPACK >> (qb * 8)) & 255);

    float mm[4], ll[4];
    float m = -1e30f;
#pragma unroll
    for (int c = 0; c < 4; ++c)
        if (c < nch) {
            const float2 v = ml[(size_t)(bh * 16 + cb + c) * 128 + rl];
            mm[c] = v.x; ll[c] = v.y;
            m = fmaxf(m, v.x);
        }
    float wc[4], wsum = 0.f;
#pragma unroll
    for (int c = 0; c < 4; ++c)
        if (c < nch) { wc[c] = ll[c] * __expf(mm[c] - m); wsum += wc[c]; }
    const float inv = (wsum > 0.f) ? 1.f / wsum : 0.f;

    float o[8] = {0.f, 0.f, 0.f, 0.f, 0.f, 0.f, 0.f, 0.f};
#pragma unroll
    for (int c = 0; c < 4; ++c)
        if (c < nch) {
            union { int4 v; ushort u[8]; } p;
            p.v = *reinterpret_cast<const int4*>(
                &ctxP[((size_t)(bh * 16 + cb + c) * 128 + rl) * 64 + dk0]);
            const float wgt = wc[c] * inv;
#pragma unroll
            for (int i = 0; i < 8; ++i)
                o[i] += wgt * __uint_as_float((unsigned)p.u[i] << 16);
        }
    union { int4 v; ushort u[8]; } r;
#pragma unroll
    for (int i = 0; i < 8; ++i) r.u[i] = (ushort)bf16rne(o[i]);
    *reinterpret_cast<int4*>(ctx + idx) = r.v;
}

// ---------------------------------------------------------------------------
// LayerNorm over last dim (1024).
// ---------------------------------------------------------------------------
__global__ __launch_bounds__(256) void layernorm_k(
    const float* __restrict__ x, const float* __restrict__ gamma,
    const float* __restrict__ beta, float* __restrict__ out)
{
    const int row = blockIdx.x;
    const int t   = threadIdx.x;
    const float4 v = *reinterpret_cast<const float4*>(&x[(size_t)row * D_ + (t << 2)]);
    float sum = v.x + v.y + v.z + v.w;
    float sq  = v.x * v.x + v.y * v.y + v.z * v.z + v.w * v.w;
#pragma unroll
    for (int w = 1; w < 64; w <<= 1) {
        sum += __shfl_xor(sum, w, 64);
        sq  += __shfl_xor(sq,  w, 64);
    }
    __shared__ float red[8];
    const int wid = t >> 6;
    if ((t & 63) == 0) { red[wid] = sum; red[wid + 4] = sq; }
    __syncthreads();
    sum = red[0] + red[1] + red[2] + red[3];
    sq  = red[4] + red[5] + red[6] + red[7];
    const float mu  = sum * (1.f / 1024.f);
    const float var = sq * (1.f / 1024.f) - mu * mu;
    const float rs  = rsqrtf(var + 1e-5f);
    const float4 gm = *reinterpret_cast<const float4*>(&gamma[t << 2]);
    const float4 bt = *reinterpret_cast<const float4*>(&beta[t << 2]);
    float4 o;
    o.x = (v.x - mu) * rs * gm.x + bt.x;
    o.y = (v.y - mu) * rs * gm.y + bt.y;
    o.z = (v.z - mu) * rs * gm.z + bt.z;
    o.w = (v.w - mu) * rs * gm.w + bt.w;
    *reinterpret_cast<float4*>(&out[(size_t)row * D_ + (t << 2)]) = o;
}

// ---------------------------------------------------------------------------
extern "C" void kernel_launch(void* const* d_in, const int* in_sizes, int n_in,
                              void* d_out, int out_size, void* d_ws, size_t ws_size,
                              hipStream_t stream)
{
    const float* query  = (const float*)d_in[0];
    const float* key    = (const float*)d_in[1];
    const float* values = (const float*)d_in[2];
    const float* SW     = (const float*)d_in[4];
    const float* Wq     = (const float*)d_in[5];
    const float* bq     = (const float*)d_in[6];
    const float* Wv     = (const float*)d_in[7];
    const float* bv     = (const float*)d_in[8];
    const float* Wo     = (const float*)d_in[9];
    const float* bo     = (const float*)d_in[10];
    const float* gamma  = (const float*)d_in[11];
    const float* beta   = (const float*)d_in[12];

    char* ws = (char*)d_ws;
    const size_t MB = 1024 * 1024;
    ushort* Qh   = (ushort*)(ws);              //  8 MB bf16 [bh][S][DK] (pre-scaled 1/8)
    ushort* Kh   = (ushort*)(ws +  8 * MB);
    ushort* Vt   = (ushort*)(ws + 16 * MB);    //  8 MB bf16 [bh][DK][S]
    ushort* Wqt  = (ushort*)(ws + 24 * MB);    //  2 MB each
    ushort* Wvt  = (ushort*)(ws + 26 * MB);
    ushort* Wot  = (ushort*)(ws + 28 * MB);
    ushort* ctxP = (ushort*)(ws + 30 * MB);    // 16 MB partials (30..46)
    float2* ml   = (float2*)(ws + 46 * MB);    //  1 MB
    ushort* ctxm = Qh;                         //  8 MB merged, overlays Qh (dead post-attn)
    float*  xbf  = (float*)(ws + 8 * MB);      // 16 MB fp32, overlays Kh|Vt (dead post-attn)

    const dim3 blk(256);

    transpose_cvt3<<<dim3(32, 32, 3), blk, 0, stream>>>(Wq, Wv, Wo, Wqt, Wvt, Wot);

    gemm_qkv<<<dim3(1536), blk, 0, stream>>>(query, key, values, Wqt, Wvt,
                                             bq, bv, Qh, Kh, Vt);

    attn_mfma<<<dim3(1024), blk, 0, stream>>>(Qh, Kh, Vt, SW, ctxP, ml);
    attn_merge<<<dim3(2048), blk, 0, stream>>>(ctxP, ml, ctxm);

    gemm_bf16a<<<dim3(512), blk, 0, stream>>>(ctxm, Wot, bo, query, xbf);

    layernorm_k<<<dim3(4096), blk, 0, stream>>>(xbf, gamma, beta, (float*)d_out);
}

// Round 15
// 120.710 us; speedup vs baseline: 2.4586x; 1.0651x over previous
//
#include <hip/hip_runtime.h>

#define B_ 4
#define S_ 1024
#define D_ 1024
#define H_ 16
#define DK_ 64

typedef __attribute__((ext_vector_type(8))) short short8;
typedef __attribute__((ext_vector_type(4))) float f32x4;
typedef __attribute__((ext_vector_type(16))) float f32x16;

// 16 chunks per bh covering 72 k-tiles: nibble i = chunk i's {qb, t0, nt}
#define QBPACK 0x7777666554433210ULL
#define T0PACK 0xC840A50605040000ULL
#define NTPACK 0x4444455665544642ULL
// per-qb: first chunk index (byte) and chunk count (nibble)
#define CBPACK  0x0C09070503020100ULL
#define NCHPACK 0x43222111U

static __device__ __forceinline__ unsigned bf16rne(float x) {
    unsigned b = __float_as_uint(x);
    return (b + 0x7FFFu + ((b >> 16) & 1u)) >> 16;
}

// ---------------------------------------------------------------------------
// W [1024][1024] fp32 -> Wt [n][k] bf16 (transpose + convert). z selects W.
// ---------------------------------------------------------------------------
__global__ __launch_bounds__(256) void transpose_cvt3(
    const float* __restrict__ W0, const float* __restrict__ W1,
    const float* __restrict__ W2, ushort* __restrict__ T0,
    ushort* __restrict__ T1, ushort* __restrict__ T2)
{
    __shared__ float ts[32][33];
    const float* W = (blockIdx.z == 0) ? W0 : (blockIdx.z == 1) ? W1 : W2;
    ushort*     Wt = (blockIdx.z == 0) ? T0 : (blockIdx.z == 1) ? T1 : T2;
    const int t  = threadIdx.x;
    const int k0 = blockIdx.y * 32, n0 = blockIdx.x * 32;
    const int r  = t >> 3, c4 = (t & 7) * 4;
    const float4 v = *reinterpret_cast<const float4*>(&W[(size_t)(k0 + r) * 1024 + n0 + c4]);
    ts[r][c4] = v.x; ts[r][c4 + 1] = v.y; ts[r][c4 + 2] = v.z; ts[r][c4 + 3] = v.w;
    __syncthreads();
    ushort4 o;
    o.x = (ushort)bf16rne(ts[c4    ][r]);
    o.y = (ushort)bf16rne(ts[c4 + 1][r]);
    o.z = (ushort)bf16rne(ts[c4 + 2][r]);
    o.w = (ushort)bf16rne(ts[c4 + 3][r]);
    *reinterpret_cast<ushort4*>(&Wt[(size_t)(n0 + r) * 1024 + k0 + c4]) = o;
}

// ---------------------------------------------------------------------------
// Merged QKV projection GEMM, fp32-A fused convert, m97 geometry:
// BM=128, BN=128, BK=64; 4 waves (2x2), 4x4 frags of 16x16x32 = 32 MFMA per
// wave per K-step (2x R14 -> staging stalls amortized). Grid 768 = 3/CU.
// A: 8xfloat4 reg-stage -> cvt_pk -> 4 ds_write_b128; B: global_load_lds.
// Order-pinned body; vmcnt(8) = B's 4 ops drained, A(kt+1)'s 8 in flight.
// bm 0..31 -> Q (x1/8, headed), 32..63 -> K (headed), 64..95 -> V (tr).
// ---------------------------------------------------------------------------
__global__ __launch_bounds__(256, 3) void gemm_qkv(
    const float* __restrict__ q, const float* __restrict__ k,
    const float* __restrict__ v, const ushort* __restrict__ Wqt,
    const ushort* __restrict__ Wvt, const float* __restrict__ bq,
    const float* __restrict__ bv, ushort* __restrict__ Qh,
    ushort* __restrict__ Kh, ushort* __restrict__ Vt)
{
    __shared__ ushort As[128 * 64];    // 16 KB
    __shared__ ushort Bs[128 * 64];    // 16 KB

    const int t    = threadIdx.x;
    const int lane = t & 63;
    const int w    = t >> 6;

    const int cpx     = gridDim.x >> 3;              // 96
    const int logical = (blockIdx.x & 7) * cpx + (blockIdx.x >> 3);
    const int bm = logical >> 3;                     // 0..95
    const int bn = logical & 7;

    const int mode = bm >> 5;                        // 0=Q, 1=K, 2=V
    const float* Xf = (mode == 0) ? q : (mode == 1) ? k : v;
    const ushort* Wt = (mode == 2) ? Wvt : Wqt;
    const float* bias = (mode == 2) ? bv : bq;
    const int rbase = (bm & 31) * 128;

    const int srow   = lane >> 3;
    const int schunk = (lane & 7) ^ srow;
    const float* ap[4];
#pragma unroll
    for (int j = 0; j < 4; ++j)
        ap[j] = Xf + (size_t)(rbase + (j * 4 + w) * 8 + srow) * 1024 + schunk * 8;

    const ushort* bg[4];
#pragma unroll
    for (int j = 0; j < 4; ++j)
        bg[j] = Wt + (size_t)(bn * 128 + (j * 4 + w) * 8 + srow) * 1024 + schunk * 8;

    // ONE named A register set: 8x float4 = 32 VGPR (rows group j: fjx,fjy)
    float4 f0x, f0y, f1x, f1y, f2x, f2y, f3x, f3y;

#define A_ISSUE(k0)                                                              \
    do {                                                                         \
        f0x = *reinterpret_cast<const float4*>(ap[0] + (k0));                    \
        f0y = *reinterpret_cast<const float4*>(ap[0] + (k0) + 4);                \
        f1x = *reinterpret_cast<const float4*>(ap[1] + (k0));                    \
        f1y = *reinterpret_cast<const float4*>(ap[1] + (k0) + 4);                \
        f2x = *reinterpret_cast<const float4*>(ap[2] + (k0));                    \
        f2y = *reinterpret_cast<const float4*>(ap[2] + (k0) + 4);                \
        f3x = *reinterpret_cast<const float4*>(ap[3] + (k0));                    \
        f3y = *reinterpret_cast<const float4*>(ap[3] + (k0) + 4);                \
    } while (0)

#define B_STAGE(k0)                                                              \
    do {                                                                         \
        _Pragma("unroll")                                                        \
        for (int j = 0; j < 4; ++j)                                              \
            __builtin_amdgcn_global_load_lds(                                    \
                (__attribute__((address_space(1))) const void*)(bg[j] + (k0)),   \
                (__attribute__((address_space(3))) void*)&Bs[(j * 4 + w) * 512], \
                16, 0, 0);                                                       \
    } while (0)

#define CVT1(dst, X, Y)                                                          \
    do {                                                                         \
        asm("v_cvt_pk_bf16_f32 %0, %1, %2" : "=v"(dst.u[0]) : "v"(X.x), "v"(X.y)); \
        asm("v_cvt_pk_bf16_f32 %0, %1, %2" : "=v"(dst.u[1]) : "v"(X.z), "v"(X.w)); \
        asm("v_cvt_pk_bf16_f32 %0, %1, %2" : "=v"(dst.u[2]) : "v"(Y.x), "v"(Y.y)); \
        asm("v_cvt_pk_bf16_f32 %0, %1, %2" : "=v"(dst.u[3]) : "v"(Y.z), "v"(Y.w)); \
    } while (0)

#define A_WRITE()                                                                \
    do {                                                                         \
        union { unsigned u[4]; int4 v; } p0, p1, p2, p3;                         \
        CVT1(p0, f0x, f0y);                                                      \
        CVT1(p1, f1x, f1y);                                                      \
        CVT1(p2, f2x, f2y);                                                      \
        CVT1(p3, f3x, f3y);                                                      \
        *reinterpret_cast<int4*>(&As[((0 * 4 + w) * 64 + lane) * 8]) = p0.v;     \
        *reinterpret_cast<int4*>(&As[((1 * 4 + w) * 64 + lane) * 8]) = p1.v;     \
        *reinterpret_cast<int4*>(&As[((2 * 4 + w) * 64 + lane) * 8]) = p2.v;     \
        *reinterpret_cast<int4*>(&As[((3 * 4 + w) * 64 + lane) * 8]) = p3.v;     \
    } while (0)

    const int fr = lane & 15;
    const int fk = lane >> 4;
    const int wm = w >> 1, wn = w & 1;

    f32x4 acc[4][4];
#pragma unroll
    for (int m = 0; m < 4; ++m)
#pragma unroll
        for (int n = 0; n < 4; ++n) acc[m][n] = (f32x4){0.f, 0.f, 0.f, 0.f};

#define MFMA_TILE()                                                              \
    do {                                                                         \
        _Pragma("unroll")                                                        \
        for (int ks = 0; ks < 2; ++ks) {                                         \
            short8 af[4], bf[4];                                                 \
            _Pragma("unroll")                                                    \
            for (int m = 0; m < 4; ++m) {                                        \
                const int row = wm * 64 + m * 16 + fr;                           \
                af[m] = *reinterpret_cast<const short8*>(                        \
                    &As[row * 64 + (((ks * 4 + fk) ^ (row & 7)) * 8)]);          \
            }                                                                    \
            _Pragma("unroll")                                                    \
            for (int n = 0; n < 4; ++n) {                                        \
                const int row = wn * 64 + n * 16 + fr;                           \
                bf[n] = *reinterpret_cast<const short8*>(                        \
                    &Bs[row * 64 + (((ks * 4 + fk) ^ (row & 7)) * 8)]);          \
            }                                                                    \
            __builtin_amdgcn_s_setprio(1);                                       \
            _Pragma("unroll")                                                    \
            for (int m = 0; m < 4; ++m)                                          \
                _Pragma("unroll")                                                \
                for (int n = 0; n < 4; ++n)                                      \
                    acc[m][n] = __builtin_amdgcn_mfma_f32_16x16x32_bf16(         \
                        af[m], bf[n], acc[m][n], 0, 0, 0);                       \
            __builtin_amdgcn_s_setprio(0);                                       \
        }                                                                        \
    } while (0)

    // body: entry outstanding = A(kt)'s 8 ops. Order pinned so the counts
    // hold: after issues, outstanding = B(4, oldest) + A(kt+1)(8) = 12;
    // vmcnt(8) drains exactly the B ops.
#define BODY(kt)                                                                 \
    do {                                                                         \
        asm volatile("s_waitcnt vmcnt(0)" ::: "memory");  /* A(kt) landed */     \
        __builtin_amdgcn_sched_barrier(0);                                       \
        A_WRITE();                                        /* A(kt) -> As */      \
        __builtin_amdgcn_sched_barrier(0);                                       \
        B_STAGE((kt) * 64);                               /* B(kt) -> Bs */      \
        __builtin_amdgcn_sched_barrier(0);                                       \
        A_ISSUE((((kt) + 1) & 15) * 64);                  /* A(kt+1) -> regs */  \
        __builtin_amdgcn_sched_barrier(0);                                       \
        asm volatile("s_waitcnt vmcnt(8) lgkmcnt(0)" ::: "memory"); /* B done */ \
        __builtin_amdgcn_s_barrier();                                            \
        __builtin_amdgcn_sched_barrier(0);                                       \
        MFMA_TILE();                                                             \
        __builtin_amdgcn_sched_barrier(0);                                       \
        __builtin_amdgcn_s_barrier();                                            \
        __builtin_amdgcn_sched_barrier(0);                                       \
    } while (0)

    A_ISSUE(0);
#pragma unroll 1
    for (int kt = 0; kt < 16; ++kt) {
        BODY(kt);
    }
#undef A_ISSUE
#undef B_STAGE
#undef CVT1
#undef A_WRITE
#undef MFMA_TILE
#undef BODY

#pragma unroll
    for (int m = 0; m < 4; ++m) {
        const int row0 = rbase + wm * 64 + m * 16 + fk * 4;
#pragma unroll
        for (int n = 0; n < 4; ++n) {
            const int col = bn * 128 + wn * 64 + n * 16 + fr;
            const float bc = bias[col];
            const int b_ = row0 >> 10, s0 = row0 & 1023;
            const int h  = col >> 6,   dk = col & 63;
            if (mode == 0) {
#pragma unroll
                for (int j = 0; j < 4; ++j)
                    Qh[(((size_t)b_ * H_ + h) * S_ + s0 + j) * DK_ + dk] =
                        (ushort)bf16rne((acc[m][n][j] + bc) * 0.125f);
            } else if (mode == 1) {
#pragma unroll
                for (int j = 0; j < 4; ++j)
                    Kh[(((size_t)b_ * H_ + h) * S_ + s0 + j) * DK_ + dk] =
                        (ushort)bf16rne(acc[m][n][j] + bc);
            } else {
                ushort4 pk;
                pk.x = (ushort)bf16rne(acc[m][n][0] + bc);
                pk.y = (ushort)bf16rne(acc[m][n][1] + bc);
                pk.z = (ushort)bf16rne(acc[m][n][2] + bc);
                pk.w = (ushort)bf16rne(acc[m][n][3] + bc);
                *reinterpret_cast<ushort4*>(
                    &Vt[(((size_t)b_ * H_ + h) * DK_ + dk) * S_ + s0]) = pk;
            }
        }
    }
}

// ---------------------------------------------------------------------------
// bf16-A MFMA GEMM (output projection): C = ctx @ Wt^T + bias + resid (fp32).
// ---------------------------------------------------------------------------
__global__ __launch_bounds__(256) void gemm_bf16a(
    const ushort* __restrict__ X, const ushort* __restrict__ Wt,
    const float* __restrict__ bias, const float* __restrict__ resid,
    float* __restrict__ out)
{
    __shared__ ushort As[2][64 * 64];
    __shared__ ushort Bs[2][128 * 64];

    const int t    = threadIdx.x;
    const int lane = t & 63;
    const int w    = t >> 6;

    const int cpx     = gridDim.x >> 3;
    const int logical = (blockIdx.x & 7) * cpx + (blockIdx.x >> 3);
    const int bm = logical >> 3;
    const int bn = logical & 7;

    const int srow   = lane >> 3;
    const int schunk = (lane & 7) ^ srow;
    const ushort* ag[2];
    const ushort* bg[4];
#pragma unroll
    for (int j = 0; j < 2; ++j)
        ag[j] = X  + (size_t)(bm * 64 + (j * 4 + w) * 8 + srow) * 1024 + schunk * 8;
#pragma unroll
    for (int j = 0; j < 4; ++j)
        bg[j] = Wt + (size_t)(bn * 128 + (j * 4 + w) * 8 + srow) * 1024 + schunk * 8;

#define STAGE(buf, k0)                                                           \
    do {                                                                         \
        _Pragma("unroll")                                                        \
        for (int j = 0; j < 2; ++j)                                              \
            __builtin_amdgcn_global_load_lds(                                    \
                (__attribute__((address_space(1))) const void*)(ag[j] + (k0)),   \
                (__attribute__((address_space(3))) void*)&As[buf][(j * 4 + w) * 512], \
                16, 0, 0);                                                       \
        _Pragma("unroll")                                                        \
        for (int j = 0; j < 4; ++j)                                              \
            __builtin_amdgcn_global_load_lds(                                    \
                (__attribute__((address_space(1))) const void*)(bg[j] + (k0)),   \
                (__attribute__((address_space(3))) void*)&Bs[buf][(j * 4 + w) * 512], \
                16, 0, 0);                                                       \
    } while (0)

    const int fr = lane & 15;
    const int fk = lane >> 4;
    const int wm = w >> 1, wn = w & 1;

    f32x4 acc[2][4];
#pragma unroll
    for (int m = 0; m < 2; ++m)
#pragma unroll
        for (int n = 0; n < 4; ++n) acc[m][n] = (f32x4){0.f, 0.f, 0.f, 0.f};

    STAGE(0, 0);
#pragma unroll 1
    for (int kt = 0; kt < 16; ++kt) {
        const int cur = kt & 1;
        if (kt + 1 < 16) {
            STAGE(cur ^ 1, (kt + 1) * 64);
            asm volatile("s_waitcnt vmcnt(6)" ::: "memory");
        } else {
            asm volatile("s_waitcnt vmcnt(0)" ::: "memory");
        }
        __builtin_amdgcn_s_barrier();
        __builtin_amdgcn_sched_barrier(0);
#pragma unroll
        for (int ks = 0; ks < 2; ++ks) {
            short8 af[2], bf[4];
#pragma unroll
            for (int m = 0; m < 2; ++m) {
                const int row = wm * 32 + m * 16 + fr;
                af[m] = *reinterpret_cast<const short8*>(
                    &As[cur][row * 64 + (((ks * 4 + fk) ^ (row & 7)) * 8)]);
            }
#pragma unroll
            for (int n = 0; n < 4; ++n) {
                const int row = wn * 64 + n * 16 + fr;
                bf[n] = *reinterpret_cast<const short8*>(
                    &Bs[cur][row * 64 + (((ks * 4 + fk) ^ (row & 7)) * 8)]);
            }
            __builtin_amdgcn_s_setprio(1);
#pragma unroll
            for (int m = 0; m < 2; ++m)
#pragma unroll
                for (int n = 0; n < 4; ++n)
                    acc[m][n] = __builtin_amdgcn_mfma_f32_16x16x32_bf16(
                        af[m], bf[n], acc[m][n], 0, 0, 0);
            __builtin_amdgcn_s_setprio(0);
        }
        __builtin_amdgcn_sched_barrier(0);
        __builtin_amdgcn_s_barrier();
        __builtin_amdgcn_sched_barrier(0);
    }
#undef STAGE

#pragma unroll
    for (int m = 0; m < 2; ++m) {
        const int row0 = bm * 64 + wm * 32 + m * 16 + fk * 4;
#pragma unroll
        for (int n = 0; n < 4; ++n) {
            const int col = bn * 128 + wn * 64 + n * 16 + fr;
            const float bc = bias[col];
#pragma unroll
            for (int j = 0; j < 4; ++j) {
                const int row = row0 + j;
                out[(size_t)row * 1024 + col] =
                    acc[m][n][j] + bc + resid[(size_t)row * 1024 + col];
            }
        }
    }
}

// ---------------------------------------------------------------------------
// MFMA bf16 flash attention v8 (unchanged): 1024 blocks (64 bh x 16
// table-driven chunks), fragment-major LDS, counted vmcnt dbuf, SW-first.
// ---------------------------------------------------------------------------
__global__ __launch_bounds__(256) void attn_mfma(
    const ushort* __restrict__ Qh, const ushort* __restrict__ Kh,
    const ushort* __restrict__ Vt, const float* __restrict__ SW,
    ushort* __restrict__ ctxP, float2* __restrict__ ml)
{
    __shared__ ushort Ks[2][4096];
    __shared__ ushort Vs[2][4096];

    const int t    = threadIdx.x;
    const int lane = t & 63;
    const int w    = t >> 6;
    const int lg = (blockIdx.x & 7) * 128 + (blockIdx.x >> 3);
    const int b  = lg & 3;
    const int hc = lg >> 2;
    const int h  = hc >> 4;
    const int ci = hc & 15;
    const int bh = b * 16 + h;
    const int qb = (int)((QBPACK >> (ci * 4)) & 15);
    const int t0 = (int)((T0PACK >> (ci * 4)) & 15);
    const int nt = (int)((NTPACK >> (ci * 4)) & 15);

    const int ql = lane & 31;
    const int hi = lane >> 5;
    const int qrow = qb * 128 + ql * 4 + w;

    const ushort* Kg  = Kh + (size_t)bh * S_ * DK_;
    const ushort* Vg  = Vt + (size_t)bh * DK_ * S_;
    const float*  swp = SW + ((size_t)h * S_ + qrow) * S_;

    const ushort* kgp[2];
    const ushort* vgp[2];
#pragma unroll
    for (int j = 0; j < 2; ++j) {
        const int bb = w * 2 + j;
        const int g = bb >> 2, c = bb & 3;
        kgp[j] = Kg + (size_t)(g * 32 + ql) * DK_ + c * 16 + hi * 8;
        vgp[j] = Vg + (size_t)(g * 32 + ql) * S_  + c * 16 + hi * 8;
    }

#define ASTAGE(buf, k0)                                                          \
    do {                                                                         \
        _Pragma("unroll")                                                        \
        for (int j = 0; j < 2; ++j) {                                            \
            const int bb = w * 2 + j;                                            \
            __builtin_amdgcn_global_load_lds(                                    \
                (__attribute__((address_space(1))) const void*)(kgp[j] + (size_t)(k0) * DK_), \
                (__attribute__((address_space(3))) void*)&Ks[buf][bb * 512],     \
                16, 0, 0);                                                       \
            __builtin_amdgcn_global_load_lds(                                    \
                (__attribute__((address_space(1))) const void*)(vgp[j] + (k0)),  \
                (__attribute__((address_space(3))) void*)&Vs[buf][bb * 512],     \
                16, 0, 0);                                                       \
        }                                                                        \
    } while (0)

    short8 qf[4];
    {
        const ushort* Qg = Qh + ((size_t)bh * S_ + qrow) * DK_;
#pragma unroll
        for (int c = 0; c < 4; ++c) {
            union { int4 i; short8 s; } u;
            u.i = *reinterpret_cast<const int4*>(&Qg[c * 16 + hi * 8]);
            qf[c] = u.s;
        }
    }

    f32x16 accA, accB;
#pragma unroll
    for (int r = 0; r < 16; ++r) { accA[r] = 0.f; accB[r] = 0.f; }
    float mrow = -1e30f, lrow = 0.f;

    ASTAGE(0, t0 * 64);

#pragma unroll 1
    for (int kt = 0; kt < nt; ++kt) {
        const int cur = kt & 1;
        const int k0  = (t0 + kt) * 64;
        if (kt + 1 < nt) {
            ASTAGE(cur ^ 1, (t0 + kt + 1) * 64);
            asm volatile("s_waitcnt vmcnt(4)" ::: "memory");
        } else {
            asm volatile("s_waitcnt vmcnt(0)" ::: "memory");
        }
        __builtin_amdgcn_s_barrier();
        __builtin_amdgcn_sched_barrier(0);

        float swv[2][16];
#pragma unroll
        for (int g = 0; g < 2; ++g)
#pragma unroll
            for (int j = 0; j < 4; ++j) {
                const float4 v = *reinterpret_cast<const float4*>(
                    &swp[k0 + g * 32 + hi * 4 + j * 8]);
                swv[g][j * 4 + 0] = v.x; swv[g][j * 4 + 1] = v.y;
                swv[g][j * 4 + 2] = v.z; swv[g][j * 4 + 3] = v.w;
            }

        f32x16 sc[2];
        __builtin_amdgcn_s_setprio(1);
#pragma unroll
        for (int g = 0; g < 2; ++g) {
#pragma unroll
            for (int r = 0; r < 16; ++r) sc[g][r] = 0.f;
#pragma unroll
            for (int c = 0; c < 4; ++c) {
                const short8 kf = *reinterpret_cast<const short8*>(
                    &Ks[cur][((g * 4 + c) * 64 + lane) * 8]);
                sc[g] = __builtin_amdgcn_mfma_f32_32x32x16_bf16(kf, qf[c], sc[g], 0, 0, 0);
            }
        }
        __builtin_amdgcn_s_setprio(0);

        float pr[2][16];
        float tmax = -1e30f;
        if (t0 + kt >= 2 * qb) {
#pragma unroll
            for (int g = 0; g < 2; ++g)
#pragma unroll
                for (int r = 0; r < 16; ++r) {
                    const int key = k0 + g * 32 + (r & 3) + ((r >> 2) << 3) + (hi << 2);
                    const float s = (key < qrow) ? sc[g][r] + swv[g][r] : -1e30f;
                    pr[g][r] = s;
                    tmax = fmaxf(tmax, s);
                }
        } else {
#pragma unroll
            for (int g = 0; g < 2; ++g)
#pragma unroll
                for (int r = 0; r < 16; ++r) {
                    const float s = sc[g][r] + swv[g][r];
                    pr[g][r] = s;
                    tmax = fmaxf(tmax, s);
                }
        }
        tmax = fmaxf(tmax, __shfl_xor(tmax, 32, 64));
        const float mnew = fmaxf(mrow, tmax);
        const float corr = __expf(mrow - mnew);
        float psum = 0.f;
#pragma unroll
        for (int g = 0; g < 2; ++g)
#pragma unroll
            for (int r = 0; r < 16; ++r) {
                const float e = (pr[g][r] > -1e29f) ? __expf(pr[g][r] - mnew) : 0.f;
                pr[g][r] = e;
                psum += e;
            }
        psum += __shfl_xor(psum, 32, 64);
        lrow = lrow * corr + psum;
        mrow = mnew;
#pragma unroll
        for (int r = 0; r < 16; ++r) { accA[r] *= corr; accB[r] *= corr; }

        short8 paf[4];
#pragma unroll
        for (int g = 0; g < 2; ++g) {
            unsigned pk[8];
#pragma unroll
            for (int j = 0; j < 8; ++j) {
                unsigned r_;
                asm("v_cvt_pk_bf16_f32 %0, %1, %2"
                    : "=v"(r_) : "v"(pr[g][2 * j]), "v"(pr[g][2 * j + 1]));
                pk[j] = r_;
            }
            unsigned x0 = (unsigned)__shfl_xor((int)pk[0], 32, 64);
            unsigned x1 = (unsigned)__shfl_xor((int)pk[1], 32, 64);
            unsigned x2 = (unsigned)__shfl_xor((int)pk[2], 32, 64);
            unsigned x3 = (unsigned)__shfl_xor((int)pk[3], 32, 64);
            unsigned x4 = (unsigned)__shfl_xor((int)pk[4], 32, 64);
            unsigned x5 = (unsigned)__shfl_xor((int)pk[5], 32, 64);
            unsigned x6 = (unsigned)__shfl_xor((int)pk[6], 32, 64);
            unsigned x7 = (unsigned)__shfl_xor((int)pk[7], 32, 64);
            union { unsigned u[4]; short8 s; } a0, a1;
            a0.u[0] = hi ? x2 : pk[0];
            a0.u[1] = hi ? x3 : pk[1];
            a0.u[2] = hi ? pk[2] : x0;
            a0.u[3] = hi ? pk[3] : x1;
            a1.u[0] = hi ? x6 : pk[4];
            a1.u[1] = hi ? x7 : pk[5];
            a1.u[2] = hi ? pk[6] : x4;
            a1.u[3] = hi ? pk[7] : x5;
            paf[g * 2 + 0] = a0.s;
            paf[g * 2 + 1] = a1.s;
        }

        __builtin_amdgcn_s_setprio(1);
#pragma unroll
        for (int cc = 0; cc < 4; ++cc) {
            const short8 va = *reinterpret_cast<const short8*>(
                &Vs[cur][((0 * 4 + cc) * 64 + lane) * 8]);
            const short8 vb = *reinterpret_cast<const short8*>(
                &Vs[cur][((1 * 4 + cc) * 64 + lane) * 8]);
            accA = __builtin_amdgcn_mfma_f32_32x32x16_bf16(va, paf[cc], accA, 0, 0, 0);
            accB = __builtin_amdgcn_mfma_f32_32x32x16_bf16(vb, paf[cc], accB, 0, 0, 0);
        }
        __builtin_amdgcn_s_setprio(0);

        __builtin_amdgcn_sched_barrier(0);
        __builtin_amdgcn_s_barrier();
        __builtin_amdgcn_sched_barrier(0);
    }
#undef ASTAGE

    const float inv = (lrow > 0.f) ? 1.f / lrow : 0.f;
    ushort* crow_ = ctxP + ((size_t)(bh * 16 + ci) * 128 + (ql * 4 + w)) * 64;
#pragma unroll
    for (int g = 0; g < 4; ++g) {
        ushort4 oA, oB;
        oA.x = (ushort)bf16rne(accA[4 * g + 0] * inv);
        oA.y = (ushort)bf16rne(accA[4 * g + 1] * inv);
        oA.z = (ushort)bf16rne(accA[4 * g + 2] * inv);
        oA.w = (ushort)bf16rne(accA[4 * g + 3] * inv);
        oB.x = (ushort)bf16rne(accB[4 * g + 0] * inv);
        oB.y = (ushort)bf16rne(accB[4 * g + 1] * inv);
        oB.z = (ushort)bf16rne(accB[4 * g + 2] * inv);
        oB.w = (ushort)bf16rne(accB[4 * g + 3] * inv);
        *reinterpret_cast<ushort4*>(&crow_[g * 8 + hi * 4])      = oA;
        *reinterpret_cast<ushort4*>(&crow_[g * 8 + hi * 4 + 32]) = oB;
    }
    if (hi == 0) {
        float2 v; v.x = mrow; v.y = lrow;
        ml[(size_t)(bh * 16 + ci) * 128 + ql * 4 + w] = v;
    }
}

// ---------------------------------------------------------------------------
// Merge chunk partials (1..4 per q-row): out = sum_c w_c * o_c.
// ---------------------------------------------------------------------------
__global__ __launch_bounds__(256) void attn_merge(
    const ushort* __restrict__ ctxP, const float2* __restrict__ ml,
    ushort* __restrict__ ctx)
{
    const size_t idx = ((size_t)blockIdx.x * 256 + threadIdx.x) * 8;
    const int col = (int)(idx & 1023);
    const int row = (int)(idx >> 10);
    const int b = row >> 10, s = row & 1023;
    const int h = col >> 6, dk0 = col & 63;
    const int bh = b * 16 + h;
    const int qb = s >> 7, rl = s & 127;
    const int nch = (int)((NCHPACK >> (qb * 4)) & 15);
    const int cb  = (int)((CBPACK >> (qb * 8)) & 255);

    float mm[4], ll[4];
    float m = -1e30f;
#pragma unroll
    for (int c = 0; c < 4; ++c)
        if (c < nch) {
            const float2 v = ml[(size_t)(bh * 16 + cb + c) * 128 + rl];
            mm[c] = v.x; ll[c] = v.y;
            m = fmaxf(m, v.x);
        }
    float wc[4], wsum = 0.f;
#pragma unroll
    for (int c = 0; c < 4; ++c)
        if (c < nch) { wc[c] = ll[c] * __expf(mm[c] - m); wsum += wc[c]; }
    const float inv = (wsum > 0.f) ? 1.f / wsum : 0.f;

    float o[8] = {0.f, 0.f, 0.f, 0.f, 0.f, 0.f, 0.f, 0.f};
#pragma unroll
    for (int c = 0; c < 4; ++c)
        if (c < nch) {
            union { int4 v; ushort u[8]; } p;
            p.v = *reinterpret_cast<const int4*>(
                &ctxP[((size_t)(bh * 16 + cb + c) * 128 + rl) * 64 + dk0]);
            const float wgt = wc[c] * inv;
#pragma unroll
            for (int i = 0; i < 8; ++i)
                o[i] += wgt * __uint_as_float((unsigned)p.u[i] << 16);
        }
    union { int4 v; ushort u[8]; } r;
#pragma unroll
    for (int i = 0; i < 8; ++i) r.u[i] = (ushort)bf16rne(o[i]);
    *reinterpret_cast<int4*>(ctx + idx) = r.v;
}

// ---------------------------------------------------------------------------
// LayerNorm over last dim (1024).
// ---------------------------------------------------------------------------
__global__ __launch_bounds__(256) void layernorm_k(
    const float* __restrict__ x, const float* __restrict__ gamma,
    const float* __restrict__ beta, float* __restrict__ out)
{
    const int row = blockIdx.x;
    const int t   = threadIdx.x;
    const float4 v = *reinterpret_cast<const float4*>(&x[(size_t)row * D_ + (t << 2)]);
    float sum = v.x + v.y + v.z + v.w;
    float sq  = v.x * v.x + v.y * v.y + v.z * v.z + v.w * v.w;
#pragma unroll
    for (int w = 1; w < 64; w <<= 1) {
        sum += __shfl_xor(sum, w, 64);
        sq  += __shfl_xor(sq,  w, 64);
    }
    __shared__ float red[8];
    const int wid = t >> 6;
    if ((t & 63) == 0) { red[wid] = sum; red[wid + 4] = sq; }
    __syncthreads();
    sum = red[0] + red[1] + red[2] + red[3];
    sq  = red[4] + red[5] + red[6] + red[7];
    const float mu  = sum * (1.f / 1024.f);
    const float var = sq * (1.f / 1024.f) - mu * mu;
    const float rs  = rsqrtf(var + 1e-5f);
    const float4 gm = *reinterpret_cast<const float4*>(&gamma[t << 2]);
    const float4 bt = *reinterpret_cast<const float4*>(&beta[t << 2]);
    float4 o;
    o.x = (v.x - mu) * rs * gm.x + bt.x;
    o.y = (v.y - mu) * rs * gm.y + bt.y;
    o.z = (v.z - mu) * rs * gm.z + bt.z;
    o.w = (v.w - mu) * rs * gm.w + bt.w;
    *reinterpret_cast<float4*>(&out[(size_t)row * D_ + (t << 2)]) = o;
}

// ---------------------------------------------------------------------------
extern "C" void kernel_launch(void* const* d_in, const int* in_sizes, int n_in,
                              void* d_out, int out_size, void* d_ws, size_t ws_size,
                              hipStream_t stream)
{
    const float* query  = (const float*)d_in[0];
    const float* key    = (const float*)d_in[1];
    const float* values = (const float*)d_in[2];
    const float* SW     = (const float*)d_in[4];
    const float* Wq     = (const float*)d_in[5];
    const float* bq     = (const float*)d_in[6];
    const float* Wv     = (const float*)d_in[7];
    const float* bv     = (const float*)d_in[8];
    const float* Wo     = (const float*)d_in[9];
    const float* bo     = (const float*)d_in[10];
    const float* gamma  = (const float*)d_in[11];
    const float* beta   = (const float*)d_in[12];

    char* ws = (char*)d_ws;
    const size_t MB = 1024 * 1024;
    ushort* Qh   = (ushort*)(ws);              //  8 MB bf16 [bh][S][DK] (pre-scaled 1/8)
    ushort* Kh   = (ushort*)(ws +  8 * MB);
    ushort* Vt   = (ushort*)(ws + 16 * MB);    //  8 MB bf16 [bh][DK][S]
    ushort* Wqt  = (ushort*)(ws + 24 * MB);    //  2 MB each
    ushort* Wvt  = (ushort*)(ws + 26 * MB);
    ushort* Wot  = (ushort*)(ws + 28 * MB);
    ushort* ctxP = (ushort*)(ws + 30 * MB);    // 16 MB partials (30..46)
    float2* ml   = (float2*)(ws + 46 * MB);    //  1 MB
    ushort* ctxm = Qh;                         //  8 MB merged, overlays Qh (dead post-attn)
    float*  xbf  = (float*)(ws + 8 * MB);      // 16 MB fp32, overlays Kh|Vt (dead post-attn)

    const dim3 blk(256);

    transpose_cvt3<<<dim3(32, 32, 3), blk, 0, stream>>>(Wq, Wv, Wo, Wqt, Wvt, Wot);

    gemm_qkv<<<dim3(768), blk, 0, stream>>>(query, key, values, Wqt, Wvt,
                                            bq, bv, Qh, Kh, Vt);

    attn_mfma<<<dim3(1024), blk, 0, stream>>>(Qh, Kh, Vt, SW, ctxP, ml);
    attn_merge<<<dim3(2048), blk, 0, stream>>>(ctxP, ml, ctxm);

    gemm_bf16a<<<dim3(512), blk, 0, stream>>>(ctxm, Wot, bo, query, xbf);

    layernorm_k<<<dim3(4096), blk, 0, stream>>>(xbf, gamma, beta, (float*)d_out);
}